// Round 9
// baseline (575.414 us; speedup 1.0000x reference)
//
#include <hip/hip_runtime.h>
#include <stdint.h>

#define NCH    64
#define HID    128
#define OUTC   64
#define NNODE  20000
#define NEDGE  640000
#define FDIM   133
#define TE     32
#define TN     32
#define LN_EPS 1e-5f
#define KP1    160          // K of edge GEMM1, padded (133 -> 160 = 5*32)
#define KP2    128          // K of edge GEMM2/3
#define KN1    224          // K of node GEMM1, padded (193 -> 224 = 7*32)
#define CAGS   130          // bf16 Cagg LDS row stride (shorts)
#define NEBLK  (NEDGE / TE) // 20000 edge blocks
#define XSTR   (NEBLK / 8)  // 2500 blocks per XCD slice

typedef __attribute__((ext_vector_type(8))) short bf16x8;
typedef __attribute__((ext_vector_type(4))) float f32x4;

__device__ __forceinline__ unsigned short f2bf(float f) {
    union { float f; unsigned int i; } v; v.f = f;
    unsigned int b = v.i;
    return (unsigned short)((b + 0x7FFFu + ((b >> 16) & 1u)) >> 16);
}
#if defined(__has_builtin)
#if __has_builtin(__builtin_amdgcn_cvt_pk_bf16_f32)
#define HAVE_PK_BF16 1
#endif
#endif
__device__ __forceinline__ unsigned int f2bf_pk(float a, float b) {
#ifdef HAVE_PK_BF16
    auto r = __builtin_amdgcn_cvt_pk_bf16_f32(a, b);
    return __builtin_bit_cast(unsigned int, r);
#else
    return (unsigned int)f2bf(a) | ((unsigned int)f2bf(b) << 16);
#endif
}
__device__ __forceinline__ float bfu2f(unsigned short u) {
    union { unsigned int i; float f; } v; v.i = ((unsigned int)u) << 16; return v.f;
}
// fast softplus: hardware v_exp_f32 / v_log_f32
__device__ __forceinline__ float sp(float xv) {
    return fmaxf(xv, 0.f) + __logf(1.0f + __expf(-fabsf(xv)));
}
__device__ __forceinline__ void atomAddF(float* p, float v) {
    __hip_atomic_fetch_add(p, v, __ATOMIC_RELAXED, __HIP_MEMORY_SCOPE_AGENT);
}
// xor-butterfly via ds_swizzle with immediate pattern (no lane math)
template<int PAT> __device__ __forceinline__ float shx(float v) {
    int i = __builtin_amdgcn_ds_swizzle(__builtin_bit_cast(int, v), PAT);
    return __builtin_bit_cast(float, i);
}
#define RED16(v) { v += shx<0x041F>(v); v += shx<0x081F>(v); v += shx<0x101F>(v); v += shx<0x201F>(v); }

// A/B fragment offset in a [kstep][mtile(2)][lane(64)][8] bf16 buffer
__device__ __forceinline__ int fragOff(int ks, int mt, int lanepos) {
    return ((ks * 2 + mt) * 64 + lanepos) * 8;
}

#define WT_WE1 0
#define WT_WV1 (128 * KP1)
#define WT_WE2 (2 * 128 * KP1)
#define WT_WE3 (2 * 128 * KP1 + 128 * KP2)
#define WT_WH1 (2 * 128 * KP1 + 2 * 128 * KP2)            // 73728
#define WT_WH2 (WT_WH1 + 128 * KN1)                        // +28672
#define WT_TOTAL (WT_WH2 + 64 * KP2)                       // 110592 shorts
#define PKP_N  1153                                        // packed param floats

// ---- fused: zero mh/mv + weight transpose + param pack + degree histogram
__global__ __launch_bounds__(256)
void eg_prep(const float* __restrict__ We1, const float* __restrict__ Wv1,
             const float* __restrict__ We2, const float* __restrict__ We3,
             const float* __restrict__ Wh1, const float* __restrict__ Wh2,
             const float* __restrict__ be1, const float* __restrict__ bv1,
             const float* __restrict__ ge1, const float* __restrict__ bte1,
             const float* __restrict__ gv1, const float* __restrict__ btv1,
             const float* __restrict__ Wv2, const float* __restrict__ be2,
             const float* __restrict__ be3, const float* __restrict__ bv2,
             const int* __restrict__ ei,
             short* __restrict__ wt, float* __restrict__ pkp,
             int* __restrict__ deg, float* __restrict__ mhz)
{
    int idx = blockIdx.x * 256 + threadIdx.x;   // 0 .. 639999
    // zero mh (2.56M f) + mv (40k f) = 650,000 float4
    {
        float4 z = {0.f, 0.f, 0.f, 0.f};
        ((float4*)mhz)[idx] = z;
        if (idx < 10000) ((float4*)mhz)[640000 + idx] = z;
    }
    if (idx < WT_TOTAL) {
        short v;
        if (idx < WT_WV1) {
            int n = idx / KP1, k = idx % KP1;
            v = (k < FDIM) ? (short)f2bf(We1[(size_t)k * HID + n]) : (short)0;
        } else if (idx < WT_WE2) {
            int r = idx - WT_WV1; int n = r / KP1, k = r % KP1;
            v = (k < FDIM) ? (short)f2bf(Wv1[(size_t)k * HID + n]) : (short)0;
        } else if (idx < WT_WE3) {
            int r = idx - WT_WE2; int n = r / KP2, k = r % KP2;
            v = (short)f2bf(We2[(size_t)k * HID + n]);
        } else if (idx < WT_WH1) {
            int r = idx - WT_WE3; int n = r / KP2, k = r % KP2;
            v = (short)f2bf(We3[(size_t)k * HID + n]);
        } else if (idx < WT_WH2) {
            int r = idx - WT_WH1; int n = r / KN1, k = r % KN1;
            v = (k < 193) ? (short)f2bf(Wh1[(size_t)k * HID + n]) : (short)0;
        } else {
            int r = idx - WT_WH2; int n = r / KP2, k = r % KP2;
            v = (short)f2bf(Wh2[(size_t)k * OUTC + n]);
        }
        wt[idx] = v;
    }
    if (idx < PKP_N) {
        float pv;
        int k = idx >> 7, c = idx & 127;
        switch (k) {
            case 0: pv = be1[c]; break;
            case 1: pv = bv1[c]; break;
            case 2: pv = ge1[c]; break;
            case 3: pv = bte1[c]; break;
            case 4: pv = gv1[c]; break;
            case 5: pv = btv1[c]; break;
            case 6: pv = Wv2[c]; break;
            case 7: pv = be2[c]; break;
            case 8: pv = be3[c]; break;
            default: pv = bv2[0]; break;   // idx == 1152
        }
        pkp[idx] = pv;
    }
    if (idx < NEDGE)
        __hip_atomic_fetch_add(&deg[ei[NEDGE + idx]], 1, __ATOMIC_RELAXED, __HIP_MEMORY_SCOPE_AGENT);
}

// ------------------------------------------------- exclusive scan -> cursor
__global__ __launch_bounds__(1024)
void eg_scan(const int* __restrict__ deg, int* __restrict__ cur)
{
    __shared__ int part[1024];
    const int tid = threadIdx.x;
    const int chunk = (NNODE + 1023) / 1024;   // 20
    const int base = tid * chunk;
    const int lim = min(base + chunk, NNODE);
    int s = 0;
    for (int j = base; j < lim; ++j) s += deg[j];
    part[tid] = s;
    __syncthreads();
    for (int off = 1; off < 1024; off <<= 1) {
        int v = (tid >= off) ? part[tid - off] : 0;
        __syncthreads();
        part[tid] += v;
        __syncthreads();
    }
    int run = (tid > 0) ? part[tid - 1] : 0;
    for (int j = base; j < lim; ++j) { cur[j] = run; run += deg[j]; }
}

// ------------------------------------------------- dst-sorted permutation
__global__ __launch_bounds__(256)
void eg_scatter(const int* __restrict__ ei, int* __restrict__ cur,
                int* __restrict__ perm)
{
    int i = blockIdx.x * 256 + threadIdx.x;
    if (i < NEDGE) {
        int d = ei[NEDGE + i];
        int p = __hip_atomic_fetch_add(&cur[d], 1, __ATOMIC_RELAXED, __HIP_MEMORY_SCOPE_AGENT);
        perm[p] = i;
    }
}

// ---------------------------------------------------------------- edge kernel
__global__ __launch_bounds__(256, 8)
void eg_edge(const float* __restrict__ x, const float* __restrict__ pos,
             const float* __restrict__ vel,
             const float* __restrict__ pkp,
             const short* __restrict__ wt,
             const int* __restrict__ ei, const int* __restrict__ perm,
             float* __restrict__ mh, float* __restrict__ mv)
{
    // cagg (32*130 u16 = 8320 B) is ALIASED onto frag_s: A3 fragment reads
    // finish before the aliased write (extra barrier in P6).
    __shared__ __align__(16) short frag_s[5 * 2 * 64 * 8];        // 10240 B
    __shared__ float psum_s[512];                                  // 2048 B
    __shared__ float mu_s[64], rs_s[64];
    __shared__ int   dst_s[TE], src_s[TE];
    __shared__ float rel_s[TE * 2], vw_s[TE];

    const int tid  = threadIdx.x;
    const int lane = tid & 63;
    const int wid  = tid >> 6;
    const int lr   = lane & 15;
    const int quad = lane >> 4;
    const int n0w  = wid * 32;
    // XCD-aware swizzle: XCD (bid & 7) gets a CONTIGUOUS dst-sorted slice,
    // so its mh slice (~1.3 MB) and x[dst] rows stay resident in its 4 MB L2.
    const int bid  = (blockIdx.x & 7) * XSTR + (blockIdx.x >> 3);
    const int e_base = bid * TE;

    const short* We1T = wt + WT_WE1;
    const short* Wv1T = wt + WT_WV1;
    const short* We2T = wt + WT_WE2;
    const short* We3T = wt + WT_WE3;

    // ---- P0: permuted indices + geometry, zero kstep-4 frag region
    float geo[5];
    if (tid < TE) {
        int gi = perm[e_base + tid];
        int eS = ei[gi];
        int eD = ei[NEDGE + gi];
        src_s[tid] = eS; dst_s[tid] = eD;
        float rx = pos[2 * eS]     - pos[2 * eD];
        float ry = pos[2 * eS + 1] - pos[2 * eD + 1];
        float vx = vel[2 * eS]     - vel[2 * eD];
        float vy = vel[2 * eS + 1] - vel[2 * eD + 1];
        float dsq = rx * rx + ry * ry;
        float dvr = vx * rx + vy * ry;
        float r2  = fminf(1.0f / (dsq + 0.05f), 20.0f);
        float r6  = fminf(r2 * r2 * r2, 400.0f);
        float r12 = fminf(r6 * r6, 160000.0f);
        geo[0] = dsq; geo[1] = dvr; geo[2] = r2; geo[3] = r6; geo[4] = r12;
        rel_s[2 * tid] = rx; rel_s[2 * tid + 1] = ry;
    }
    if (tid < 128) {
        int4 z = {0, 0, 0, 0};
        *(int4*)&frag_s[4 * 2 * 64 * 8 + tid * 8] = z;
    }
    __syncthreads();

    // ---- P1: geo + gather x into A1 fragments (packed bf16)
    if (tid < TE) {
        int off = fragOff(4, tid >> 4, (tid & 15));
        #pragma unroll
        for (int j = 0; j < 5; ++j) frag_s[off + j] = (short)f2bf(geo[j]);
    }
    {
        const int e = tid & 31, slot = tid >> 5;
        const int d = dst_s[e], s = src_s[e];
        #pragma unroll
        for (int h = 0; h < 2; ++h) {
            int o = slot + h * 8;
            int node = h ? s : d;
            int c0 = (o & 7) * 8;
            const float4 a0 = *(const float4*)&x[(size_t)node * NCH + c0];
            const float4 a1 = *(const float4*)&x[(size_t)node * NCH + c0 + 4];
            uint4 pk;
            pk.x = f2bf_pk(a0.x, a0.y); pk.y = f2bf_pk(a0.z, a0.w);
            pk.z = f2bf_pk(a1.x, a1.y); pk.w = f2bf_pk(a1.z, a1.w);
            int ks = o >> 2, kq = o & 3;
            *(uint4*)&frag_s[fragOff(ks, e >> 4, kq * 16 + (e & 15))] = pk;
        }
    }
    __syncthreads();

    const int ncol0 = n0w + lr;
    const int ncol1 = n0w + 16 + lr;
    const float* p0 = pkp + ncol0;     // single base, imm offsets k*128
    const float* p1 = pkp + ncol1;

    // ---- P2: dual GEMM1 via MFMA (M=32, N=128, K=160)
    f32x4 zero4 = {0.f, 0.f, 0.f, 0.f};
    f32x4 accE[2][2], accV[2][2];
    #pragma unroll
    for (int mt = 0; mt < 2; ++mt)
        #pragma unroll
        for (int nt = 0; nt < 2; ++nt) { accE[mt][nt] = zero4; accV[mt][nt] = zero4; }
    {
        const short* pa = &frag_s[lane * 8];
        const short* pwE0 = We1T + ncol0 * KP1 + quad * 8;
        const short* pwE1 = We1T + ncol1 * KP1 + quad * 8;
        const short* pwV0 = Wv1T + ncol0 * KP1 + quad * 8;
        const short* pwV1 = Wv1T + ncol1 * KP1 + quad * 8;
        #pragma unroll
        for (int ks = 0; ks < 5; ++ks) {
            bf16x8 af0 = *(const bf16x8*)&pa[ks * 1024];
            bf16x8 af1 = *(const bf16x8*)&pa[ks * 1024 + 512];
            bf16x8 bwE0 = *(const bf16x8*)&pwE0[ks * 32];
            bf16x8 bwE1 = *(const bf16x8*)&pwE1[ks * 32];
            bf16x8 bwV0 = *(const bf16x8*)&pwV0[ks * 32];
            bf16x8 bwV1 = *(const bf16x8*)&pwV1[ks * 32];
            accE[0][0] = __builtin_amdgcn_mfma_f32_16x16x32_bf16(af0, bwE0, accE[0][0], 0, 0, 0);
            accE[1][0] = __builtin_amdgcn_mfma_f32_16x16x32_bf16(af1, bwE0, accE[1][0], 0, 0, 0);
            accE[0][1] = __builtin_amdgcn_mfma_f32_16x16x32_bf16(af0, bwE1, accE[0][1], 0, 0, 0);
            accE[1][1] = __builtin_amdgcn_mfma_f32_16x16x32_bf16(af1, bwE1, accE[1][1], 0, 0, 0);
            accV[0][0] = __builtin_amdgcn_mfma_f32_16x16x32_bf16(af0, bwV0, accV[0][0], 0, 0, 0);
            accV[1][0] = __builtin_amdgcn_mfma_f32_16x16x32_bf16(af1, bwV0, accV[1][0], 0, 0, 0);
            accV[0][1] = __builtin_amdgcn_mfma_f32_16x16x32_bf16(af0, bwV1, accV[0][1], 0, 0, 0);
            accV[1][1] = __builtin_amdgcn_mfma_f32_16x16x32_bf16(af1, bwV1, accV[1][1], 0, 0, 0);
        }
    }
    {
        float be0 = p0[0], be_1 = p1[0];
        float bv0 = p0[128], bv_1 = p1[128];
        #pragma unroll
        for (int mt = 0; mt < 2; ++mt)
            #pragma unroll
            for (int r = 0; r < 4; ++r) {
                accE[mt][0][r] += be0; accE[mt][1][r] += be_1;
                accV[mt][0][r] += bv0; accV[mt][1][r] += bv_1;
            }
    }

    // ---- P3: LN stats in-register (ds_swizzle butterflies, imm patterns)
    #pragma unroll
    for (int mt = 0; mt < 2; ++mt)
        #pragma unroll
        for (int r = 0; r < 4; ++r) {
            float se = accE[mt][0][r] + accE[mt][1][r];
            float qe = accE[mt][0][r] * accE[mt][0][r] + accE[mt][1][r] * accE[mt][1][r];
            float sv = accV[mt][0][r] + accV[mt][1][r];
            float qv = accV[mt][0][r] * accV[mt][0][r] + accV[mt][1][r] * accV[mt][1][r];
            RED16(se); RED16(qe); RED16(sv); RED16(qv);
            if (lr == 0) {
                int row = mt * 16 + quad * 4 + r;
                psum_s[      row * 4 + wid] = se;
                psum_s[128 + row * 4 + wid] = qe;
                psum_s[256 + row * 4 + wid] = sv;
                psum_s[384 + row * 4 + wid] = qv;
            }
        }
    __syncthreads();
    if (tid < 64) {
        int p = tid >> 5, row = tid & 31;
        float s = 0.f, q = 0.f;
        #pragma unroll
        for (int w = 0; w < 4; ++w) {
            s += psum_s[p * 256 +       row * 4 + w];
            q += psum_s[p * 256 + 128 + row * 4 + w];
        }
        float mu = s * (1.0f / HID);
        float var = q * (1.0f / HID) - mu * mu;
        mu_s[p * 32 + row] = mu;
        rs_s[p * 32 + row] = rsqrtf(var + LN_EPS);
    }
    __syncthreads();

    // ---- P4: normalize in-register; E -> A2 frags, V -> vw partials
    {
        float gE0 = p0[256], gE1 = p1[256];
        float tE0 = p0[384], tE1 = p1[384];
        float gV0 = p0[512], gV1 = p1[512];
        float tV0 = p0[640], tV1 = p1[640];
        float w20 = p0[768], w21 = p1[768];
        int ks0 = ncol0 >> 5, kq0 = (ncol0 & 31) >> 3, j0 = ncol0 & 7;
        int ks1 = ncol1 >> 5, kq1 = (ncol1 & 31) >> 3, j1 = ncol1 & 7;
        short* bp0 = &frag_s[(ks0 * 128 + kq0 * 16 + quad * 4) * 8 + j0];
        short* bp1 = &frag_s[(ks1 * 128 + kq1 * 16 + quad * 4) * 8 + j1];
        #pragma unroll
        for (int mt = 0; mt < 2; ++mt)
            #pragma unroll
            for (int r = 0; r < 4; ++r) {
                int rlow = quad * 4 + r, row = mt * 16 + rlow;
                float mu = mu_s[row], rsv = rs_s[row];
                float muV = mu_s[32 + row], rsV = rs_s[32 + row];
                float h0 = sp((accE[mt][0][r] - mu) * rsv * gE0 + tE0);
                float h1 = sp((accE[mt][1][r] - mu) * rsv * gE1 + tE1);
                unsigned int ph = f2bf_pk(h0, h1);
                bp0[mt * 512 + r * 8] = (short)(ph & 0xFFFFu);
                bp1[mt * 512 + r * 8] = (short)(ph >> 16);
                float v0 = sp((accV[mt][0][r] - muV) * rsV * gV0 + tV0);
                float v1 = sp((accV[mt][1][r] - muV) * rsV * gV1 + tV1);
                float vp = v0 * w20 + v1 * w21;
                RED16(vp);
                if (lr == 0) psum_s[row * 4 + wid] = vp;
            }
    }
    __syncthreads();
    if (tid < TE) {
        float s = 0.f;
        #pragma unroll
        for (int w = 0; w < 4; ++w) s += psum_s[tid * 4 + w];
        vw_s[tid] = s + pkp[1152];
    }

    // ---- P5: GEMM2 (M=32, N=128, K=128) + softplus -> A3 fragments
    {
        f32x4 acc2[2][2];
        #pragma unroll
        for (int mt = 0; mt < 2; ++mt)
            #pragma unroll
            for (int nt = 0; nt < 2; ++nt) acc2[mt][nt] = zero4;
        {
            const short* pa = &frag_s[lane * 8];
            const short* pw0 = We2T + ncol0 * KP2 + quad * 8;
            const short* pw1 = We2T + ncol1 * KP2 + quad * 8;
            #pragma unroll
            for (int ks = 0; ks < 4; ++ks) {
                bf16x8 af0 = *(const bf16x8*)&pa[ks * 1024];
                bf16x8 af1 = *(const bf16x8*)&pa[ks * 1024 + 512];
                bf16x8 bw0 = *(const bf16x8*)&pw0[ks * 32];
                bf16x8 bw1 = *(const bf16x8*)&pw1[ks * 32];
                acc2[0][0] = __builtin_amdgcn_mfma_f32_16x16x32_bf16(af0, bw0, acc2[0][0], 0, 0, 0);
                acc2[1][0] = __builtin_amdgcn_mfma_f32_16x16x32_bf16(af1, bw0, acc2[1][0], 0, 0, 0);
                acc2[0][1] = __builtin_amdgcn_mfma_f32_16x16x32_bf16(af0, bw1, acc2[0][1], 0, 0, 0);
                acc2[1][1] = __builtin_amdgcn_mfma_f32_16x16x32_bf16(af1, bw1, acc2[1][1], 0, 0, 0);
            }
        }
        __syncthreads();   // all A2 reads done before overwriting with A3
        float b2a = p0[896], b2b = p1[896];
        int ksA = ncol0 >> 5, kqA = (ncol0 & 31) >> 3, jA = ncol0 & 7;
        int ksB = ncol1 >> 5, kqB = (ncol1 & 31) >> 3, jB = ncol1 & 7;
        short* bpA = &frag_s[(ksA * 128 + kqA * 16 + quad * 4) * 8 + jA];
        short* bpB = &frag_s[(ksB * 128 + kqB * 16 + quad * 4) * 8 + jB];
        #pragma unroll
        for (int mt = 0; mt < 2; ++mt) {
            unsigned int uA0 = f2bf_pk(sp(acc2[mt][0][0] + b2a), sp(acc2[mt][0][1] + b2a));
            unsigned int uA1 = f2bf_pk(sp(acc2[mt][0][2] + b2a), sp(acc2[mt][0][3] + b2a));
            unsigned int uB0 = f2bf_pk(sp(acc2[mt][1][0] + b2b), sp(acc2[mt][1][1] + b2b));
            unsigned int uB1 = f2bf_pk(sp(acc2[mt][1][2] + b2b), sp(acc2[mt][1][3] + b2b));
            bpA[mt * 512 +  0] = (short)(uA0 & 0xFFFFu);
            bpA[mt * 512 +  8] = (short)(uA0 >> 16);
            bpA[mt * 512 + 16] = (short)(uA1 & 0xFFFFu);
            bpA[mt * 512 + 24] = (short)(uA1 >> 16);
            bpB[mt * 512 +  0] = (short)(uB0 & 0xFFFFu);
            bpB[mt * 512 +  8] = (short)(uB0 >> 16);
            bpB[mt * 512 + 16] = (short)(uB1 & 0xFFFFu);
            bpB[mt * 512 + 24] = (short)(uB1 >> 16);
        }
    }
    __syncthreads();

    // ---- P6: GEMM3 (M=32, N=128, K=128) + bias -> bf16 Cagg (aliased LDS)
    {
        f32x4 acc3[2][2];
        #pragma unroll
        for (int mt = 0; mt < 2; ++mt)
            #pragma unroll
            for (int nt = 0; nt < 2; ++nt) acc3[mt][nt] = zero4;
        {
            const short* pa = &frag_s[lane * 8];
            const short* pw0 = We3T + ncol0 * KP2 + quad * 8;
            const short* pw1 = We3T + ncol1 * KP2 + quad * 8;
            #pragma unroll
            for (int ks = 0; ks < 4; ++ks) {
                bf16x8 af0 = *(const bf16x8*)&pa[ks * 1024];
                bf16x8 af1 = *(const bf16x8*)&pa[ks * 1024 + 512];
                bf16x8 bw0 = *(const bf16x8*)&pw0[ks * 32];
                bf16x8 bw1 = *(const bf16x8*)&pw1[ks * 32];
                acc3[0][0] = __builtin_amdgcn_mfma_f32_16x16x32_bf16(af0, bw0, acc3[0][0], 0, 0, 0);
                acc3[1][0] = __builtin_amdgcn_mfma_f32_16x16x32_bf16(af1, bw0, acc3[1][0], 0, 0, 0);
                acc3[0][1] = __builtin_amdgcn_mfma_f32_16x16x32_bf16(af0, bw1, acc3[0][1], 0, 0, 0);
                acc3[1][1] = __builtin_amdgcn_mfma_f32_16x16x32_bf16(af1, bw1, acc3[1][1], 0, 0, 0);
            }
        }
        __syncthreads();   // frag A3 reads complete before aliased cagg writes
        unsigned short* cagg_s = (unsigned short*)frag_s;
        float b3a = p0[1024], b3b = p1[1024];
        unsigned short* bpA = &cagg_s[(quad * 4) * CAGS + ncol0];
        unsigned short* bpB = &cagg_s[(quad * 4) * CAGS + ncol1];
        #pragma unroll
        for (int mt = 0; mt < 2; ++mt) {
            unsigned int uA0 = f2bf_pk(acc3[mt][0][0] + b3a, acc3[mt][0][1] + b3a);
            unsigned int uA1 = f2bf_pk(acc3[mt][0][2] + b3a, acc3[mt][0][3] + b3a);
            unsigned int uB0 = f2bf_pk(acc3[mt][1][0] + b3b, acc3[mt][1][1] + b3b);
            unsigned int uB1 = f2bf_pk(acc3[mt][1][2] + b3b, acc3[mt][1][3] + b3b);
            bpA[(mt * 16 + 0) * CAGS] = (unsigned short)(uA0 & 0xFFFFu);
            bpA[(mt * 16 + 1) * CAGS] = (unsigned short)(uA0 >> 16);
            bpA[(mt * 16 + 2) * CAGS] = (unsigned short)(uA1 & 0xFFFFu);
            bpA[(mt * 16 + 3) * CAGS] = (unsigned short)(uA1 >> 16);
            bpB[(mt * 16 + 0) * CAGS] = (unsigned short)(uB0 & 0xFFFFu);
            bpB[(mt * 16 + 1) * CAGS] = (unsigned short)(uB0 >> 16);
            bpB[(mt * 16 + 2) * CAGS] = (unsigned short)(uB1 & 0xFFFFu);
            bpB[(mt * 16 + 3) * CAGS] = (unsigned short)(uB1 >> 16);
        }
    }
    __syncthreads();

    // ---- P7: dst-run segmented atomic flush (rows sorted by dst)
    {
        const unsigned short* cagg_s = (const unsigned short*)frag_s;
        const int c = tid & 127, h = tid >> 7;
        const unsigned short* cp = &cagg_s[(h * 16) * CAGS + c];
        const int m0 = h * 16;
        float run = bfu2f(cp[0]);
        int curd = dst_s[m0];
        #pragma unroll
        for (int m = 1; m < 16; ++m) {
            int d = dst_s[m0 + m];
            float v = bfu2f(cp[m * CAGS]);
            if (d == curd) run += v;
            else { atomAddF(&mh[(size_t)curd * HID + c], run); curd = d; run = v; }
        }
        atomAddF(&mh[(size_t)curd * HID + c], run);
    }
    // ---- P8: m_v segmented flush
    if (tid < 2) {
        const int c = tid;
        float run = vw_s[0] * rel_s[c];
        int curd = dst_s[0];
        for (int m = 1; m < TE; ++m) {
            int d = dst_s[m];
            float v = vw_s[m] * rel_s[2 * m + c];
            if (d == curd) run += v;
            else { atomAddF(&mv[2 * curd + c], run); curd = d; run = v; }
        }
        atomAddF(&mv[2 * curd + c], run);
    }
}

// ---------------------------------------------------------------- node kernel (MFMA)
__global__ __launch_bounds__(256, 7)
void eg_node(const float* __restrict__ x,
             const float* __restrict__ bh1, const float* __restrict__ gh1,
             const float* __restrict__ bth1, const float* __restrict__ bh2,
             const float* __restrict__ mh, const float* __restrict__ mv,
             const int* __restrict__ deg, const short* __restrict__ wt,
             float* __restrict__ out)
{
    __shared__ __align__(16) short frag_s[7 * 2 * 64 * 8];   // 14336 B
    __shared__ float psum_s[256];
    __shared__ float mu_s[32], rs_s[32];
    __shared__ float rden_s[TN], norm_s[TN];

    const int tid  = threadIdx.x;
    const int lane = tid & 63;
    const int wid  = tid >> 6;
    const int lr   = lane & 15;
    const int quad = lane >> 4;
    const int n0w  = wid * 32;
    const int n_base = blockIdx.x * TN;

    const short* Wh1T = wt + WT_WH1;
    const short* Wh2T = wt + WT_WH2;

    if (tid < TN) {
        int n = n_base + tid;
        float den = fmaxf((float)deg[n], 1.0f);
        float rd = 1.0f / den;
        float ax = mv[2 * n] * rd + 1e-8f;
        float ay = mv[2 * n + 1] * rd + 1e-8f;
        rden_s[tid] = rd;
        norm_s[tid] = sqrtf(ax * ax + ay * ay);
    }
    if (tid < 128) {
        int4 z = {0, 0, 0, 0};
        *(int4*)&frag_s[6 * 2 * 64 * 8 + tid * 8] = z;
    }
    __syncthreads();

    {
        const int e = tid & 31, slot = tid >> 5;
        const int n = n_base + e;
        {
            int c0 = slot * 8;
            const float4 a0 = *(const float4*)&x[(size_t)n * NCH + c0];
            const float4 a1 = *(const float4*)&x[(size_t)n * NCH + c0 + 4];
            uint4 pk;
            pk.x = f2bf_pk(a0.x, a0.y); pk.y = f2bf_pk(a0.z, a0.w);
            pk.z = f2bf_pk(a1.x, a1.y); pk.w = f2bf_pk(a1.z, a1.w);
            int ks = slot >> 2, kq = slot & 3;
            *(uint4*)&frag_s[fragOff(ks, e >> 4, kq * 16 + (e & 15))] = pk;
        }
        float rd = rden_s[e];
        #pragma unroll
        for (int h = 0; h < 2; ++h) {
            int o = 8 + slot + h * 8;
            int k0 = (o - 8) * 8;
            const float4 a0 = *(const float4*)&mh[(size_t)n * HID + k0];
            const float4 a1 = *(const float4*)&mh[(size_t)n * HID + k0 + 4];
            uint4 pk;
            pk.x = f2bf_pk(a0.x * rd, a0.y * rd); pk.y = f2bf_pk(a0.z * rd, a0.w * rd);
            pk.z = f2bf_pk(a1.x * rd, a1.y * rd); pk.w = f2bf_pk(a1.z * rd, a1.w * rd);
            int ks = o >> 2, kq = o & 3;
            *(uint4*)&frag_s[fragOff(ks, e >> 4, kq * 16 + (e & 15))] = pk;
        }
    }
    if (tid < TN) {
        frag_s[fragOff(6, tid >> 4, (tid & 15))] = (short)f2bf(norm_s[tid]);
    }
    __syncthreads();

    const int ncol0 = n0w + lr;
    const int ncol1 = n0w + 16 + lr;

    f32x4 zero4 = {0.f, 0.f, 0.f, 0.f};
    f32x4 acc1[2][2];
    #pragma unroll
    for (int mt = 0; mt < 2; ++mt)
        #pragma unroll
        for (int nt = 0; nt < 2; ++nt) acc1[mt][nt] = zero4;
    {
        const short* pa = &frag_s[lane * 8];
        const short* pw0 = Wh1T + ncol0 * KN1 + quad * 8;
        const short* pw1 = Wh1T + ncol1 * KN1 + quad * 8;
        #pragma unroll
        for (int ks = 0; ks < 7; ++ks) {
            bf16x8 af0 = *(const bf16x8*)&pa[ks * 1024];
            bf16x8 af1 = *(const bf16x8*)&pa[ks * 1024 + 512];
            bf16x8 bw0 = *(const bf16x8*)&pw0[ks * 32];
            bf16x8 bw1 = *(const bf16x8*)&pw1[ks * 32];
            acc1[0][0] = __builtin_amdgcn_mfma_f32_16x16x32_bf16(af0, bw0, acc1[0][0], 0, 0, 0);
            acc1[1][0] = __builtin_amdgcn_mfma_f32_16x16x32_bf16(af1, bw0, acc1[1][0], 0, 0, 0);
            acc1[0][1] = __builtin_amdgcn_mfma_f32_16x16x32_bf16(af0, bw1, acc1[0][1], 0, 0, 0);
            acc1[1][1] = __builtin_amdgcn_mfma_f32_16x16x32_bf16(af1, bw1, acc1[1][1], 0, 0, 0);
        }
    }
    {
        float b0 = bh1[ncol0], b1 = bh1[ncol1];
        #pragma unroll
        for (int mt = 0; mt < 2; ++mt)
            #pragma unroll
            for (int r = 0; r < 4; ++r) { acc1[mt][0][r] += b0; acc1[mt][1][r] += b1; }
    }

    #pragma unroll
    for (int mt = 0; mt < 2; ++mt)
        #pragma unroll
        for (int r = 0; r < 4; ++r) {
            float s = acc1[mt][0][r] + acc1[mt][1][r];
            float q = acc1[mt][0][r] * acc1[mt][0][r] + acc1[mt][1][r] * acc1[mt][1][r];
            RED16(s); RED16(q);
            if (lr == 0) {
                int row = mt * 16 + quad * 4 + r;
                psum_s[row * 4 + wid]       = s;
                psum_s[128 + row * 4 + wid] = q;
            }
        }
    __syncthreads();
    if (tid < 32) {
        float s = 0.f, q = 0.f;
        #pragma unroll
        for (int w = 0; w < 4; ++w) {
            s += psum_s[tid * 4 + w];
            q += psum_s[128 + tid * 4 + w];
        }
        float mu = s * (1.0f / HID);
        float var = q * (1.0f / HID) - mu * mu;
        mu_s[tid] = mu;
        rs_s[tid] = rsqrtf(var + LN_EPS);
    }
    __syncthreads();

    {
        float g0 = gh1[ncol0], g1 = gh1[ncol1];
        float t0 = bth1[ncol0], t1 = bth1[ncol1];
        int ks0 = ncol0 >> 5, kq0 = (ncol0 & 31) >> 3, j0 = ncol0 & 7;
        int ks1 = ncol1 >> 5, kq1 = (ncol1 & 31) >> 3, j1 = ncol1 & 7;
        short* bp0 = &frag_s[(ks0 * 128 + kq0 * 16 + quad * 4) * 8 + j0];
        short* bp1 = &frag_s[(ks1 * 128 + kq1 * 16 + quad * 4) * 8 + j1];
        #pragma unroll
        for (int mt = 0; mt < 2; ++mt)
            #pragma unroll
            for (int r = 0; r < 4; ++r) {
                int row = mt * 16 + quad * 4 + r;
                float mu = mu_s[row], rsv = rs_s[row];
                float h0 = sp((acc1[mt][0][r] - mu) * rsv * g0 + t0);
                float h1 = sp((acc1[mt][1][r] - mu) * rsv * g1 + t1);
                unsigned int ph = f2bf_pk(h0, h1);
                bp0[mt * 512 + r * 8] = (short)(ph & 0xFFFFu);
                bp1[mt * 512 + r * 8] = (short)(ph >> 16);
            }
    }
    __syncthreads();

    {
        const int col = wid * 16 + lr;
        f32x4 acc2[2] = { zero4, zero4 };
        const short* pa = &frag_s[lane * 8];
        const short* pw = Wh2T + col * KP2 + quad * 8;
        #pragma unroll
        for (int ks = 0; ks < 4; ++ks) {
            bf16x8 af0 = *(const bf16x8*)&pa[ks * 1024];
            bf16x8 af1 = *(const bf16x8*)&pa[ks * 1024 + 512];
            bf16x8 bw = *(const bf16x8*)&pw[ks * 32];
            acc2[0] = __builtin_amdgcn_mfma_f32_16x16x32_bf16(af0, bw, acc2[0], 0, 0, 0);
            acc2[1] = __builtin_amdgcn_mfma_f32_16x16x32_bf16(af1, bw, acc2[1], 0, 0, 0);
        }
        float bo = bh2[col];
        #pragma unroll
        for (int mt = 0; mt < 2; ++mt)
            #pragma unroll
            for (int r = 0; r < 4; ++r) {
                int m = mt * 16 + quad * 4 + r;
                size_t idx = (size_t)(n_base + m) * OUTC + col;
                out[idx] = x[(size_t)(n_base + m) * NCH + col] + acc2[mt][r] + bo;
            }
    }
}

// ---------------------------------------------------------------- launch
extern "C" void kernel_launch(void* const* d_in, const int* in_sizes, int n_in,
                              void* d_out, int out_size, void* d_ws, size_t ws_size,
                              hipStream_t stream)
{
    const float* x    = (const float*)d_in[0];
    const float* pos  = (const float*)d_in[1];
    const float* vel  = (const float*)d_in[2];
    const float* We1  = (const float*)d_in[3];
    const float* be1  = (const float*)d_in[4];
    const float* ge1  = (const float*)d_in[5];
    const float* bte1 = (const float*)d_in[6];
    const float* We2  = (const float*)d_in[7];
    const float* be2  = (const float*)d_in[8];
    const float* We3  = (const float*)d_in[9];
    const float* be3  = (const float*)d_in[10];
    const float* Wv1  = (const float*)d_in[11];
    const float* bv1  = (const float*)d_in[12];
    const float* gv1  = (const float*)d_in[13];
    const float* btv1 = (const float*)d_in[14];
    const float* Wv2  = (const float*)d_in[15];
    const float* bv2  = (const float*)d_in[16];
    const float* Wh1  = (const float*)d_in[17];
    const float* bh1  = (const float*)d_in[18];
    const float* gh1  = (const float*)d_in[19];
    const float* bth1 = (const float*)d_in[20];
    const float* Wh2  = (const float*)d_in[21];
    const float* bh2  = (const float*)d_in[22];
    const int*   ei   = (const int*)d_in[23];

    // workspace layout
    float* mh   = (float*)d_ws;                      // 2,560,000 f
    float* mv   = mh + (size_t)NNODE * HID;          // 40,000 f
    int*   deg  = (int*)(mv + NNODE * 2);            // 20,000 i
    int*   cur  = deg + NNODE;                       // 20,000 i
    int*   perm = cur + NNODE;                       // 640,000 i
    float* pkp  = (float*)(perm + NEDGE);            // 1,280 f
    short* wt   = (short*)(pkp + 1280);              // 110,592 s

    // zero deg only (mh/mv zeroed inside eg_prep by its 640k threads)
    hipMemsetAsync(deg, 0, NNODE * sizeof(int), stream);

    eg_prep<<<dim3(NEDGE / 256), dim3(256), 0, stream>>>(
        We1, Wv1, We2, We3, Wh1, Wh2,
        be1, bv1, ge1, bte1, gv1, btv1, Wv2, be2, be3, bv2,
        ei, wt, pkp, deg, mh);
    eg_scan<<<dim3(1), dim3(1024), 0, stream>>>(deg, cur);
    eg_scatter<<<dim3(NEDGE / 256), dim3(256), 0, stream>>>(ei, cur, perm);

    eg_edge<<<dim3(NEBLK), dim3(256), 0, stream>>>(
        x, pos, vel, pkp, wt, ei, perm, mh, mv);

    eg_node<<<dim3(NNODE / TN), dim3(256), 0, stream>>>(
        x, bh1, gh1, bth1, bh2, mh, mv, deg, wt, (float*)d_out);
}

// Round 10
// 520.486 us; speedup vs baseline: 1.1055x; 1.1055x over previous
//
#include <hip/hip_runtime.h>
#include <stdint.h>

#define NCH    64
#define HID    128
#define OUTC   64
#define NNODE  20000
#define NEDGE  640000
#define FDIM   133
#define TE     32
#define TN     32
#define LN_EPS 1e-5f
#define KP1    160          // K of edge GEMM1, padded (133 -> 160 = 5*32)
#define KP2    128          // K of edge GEMM2/3
#define KN1    224          // K of node GEMM1, padded (193 -> 224 = 7*32)
#define CAGS   130          // bf16 Cagg LDS row stride (shorts)
#define NEBLK  (NEDGE / TE) // 20000 edge blocks
#define XSTR   (NEBLK / 8)  // 2500 blocks per XCD slice

typedef __attribute__((ext_vector_type(8))) short bf16x8;
typedef __attribute__((ext_vector_type(4))) float f32x4;

__device__ __forceinline__ unsigned short f2bf(float f) {
    union { float f; unsigned int i; } v; v.f = f;
    unsigned int b = v.i;
    return (unsigned short)((b + 0x7FFFu + ((b >> 16) & 1u)) >> 16);
}
#if defined(__has_builtin)
#if __has_builtin(__builtin_amdgcn_cvt_pk_bf16_f32)
#define HAVE_PK_BF16 1
#endif
#endif
__device__ __forceinline__ unsigned int f2bf_pk(float a, float b) {
#ifdef HAVE_PK_BF16
    auto r = __builtin_amdgcn_cvt_pk_bf16_f32(a, b);
    return __builtin_bit_cast(unsigned int, r);
#else
    return (unsigned int)f2bf(a) | ((unsigned int)f2bf(b) << 16);
#endif
}
__device__ __forceinline__ float bfu2f(unsigned short u) {
    union { unsigned int i; float f; } v; v.i = ((unsigned int)u) << 16; return v.f;
}
// fast softplus: hardware v_exp_f32 / v_log_f32
__device__ __forceinline__ float sp(float xv) {
    return fmaxf(xv, 0.f) + __logf(1.0f + __expf(-fabsf(xv)));
}
__device__ __forceinline__ void atomAddF(float* p, float v) {
    __hip_atomic_fetch_add(p, v, __ATOMIC_RELAXED, __HIP_MEMORY_SCOPE_AGENT);
}
// xor-butterfly via ds_swizzle with immediate pattern (no lane math)
template<int PAT> __device__ __forceinline__ float shx(float v) {
    int i = __builtin_amdgcn_ds_swizzle(__builtin_bit_cast(int, v), PAT);
    return __builtin_bit_cast(float, i);
}
#define RED16(v) { v += shx<0x041F>(v); v += shx<0x081F>(v); v += shx<0x101F>(v); v += shx<0x201F>(v); }

// A/B fragment offset in a [kstep][mtile(2)][lane(64)][8] bf16 buffer
__device__ __forceinline__ int fragOff(int ks, int mt, int lanepos) {
    return ((ks * 2 + mt) * 64 + lanepos) * 8;
}

#define WT_WE1 0
#define WT_WV1 (128 * KP1)
#define WT_WE2 (2 * 128 * KP1)
#define WT_WE3 (2 * 128 * KP1 + 128 * KP2)
#define WT_WH1 (2 * 128 * KP1 + 2 * 128 * KP2)            // 73728
#define WT_WH2 (WT_WH1 + 128 * KN1)                        // +28672
#define WT_TOTAL (WT_WH2 + 64 * KP2)                       // 110592 shorts
#define PKP_N  1153                                        // packed param floats

// ---- fused: weight transpose + param pack + degree histogram
__global__ __launch_bounds__(256)
void eg_prep(const float* __restrict__ We1, const float* __restrict__ Wv1,
             const float* __restrict__ We2, const float* __restrict__ We3,
             const float* __restrict__ Wh1, const float* __restrict__ Wh2,
             const float* __restrict__ be1, const float* __restrict__ bv1,
             const float* __restrict__ ge1, const float* __restrict__ bte1,
             const float* __restrict__ gv1, const float* __restrict__ btv1,
             const float* __restrict__ Wv2, const float* __restrict__ be2,
             const float* __restrict__ be3, const float* __restrict__ bv2,
             const int* __restrict__ ei,
             short* __restrict__ wt, float* __restrict__ pkp,
             int* __restrict__ deg)
{
    int idx = blockIdx.x * 256 + threadIdx.x;   // 0 .. 639999
    if (idx < WT_TOTAL) {
        short v;
        if (idx < WT_WV1) {
            int n = idx / KP1, k = idx % KP1;
            v = (k < FDIM) ? (short)f2bf(We1[(size_t)k * HID + n]) : (short)0;
        } else if (idx < WT_WE2) {
            int r = idx - WT_WV1; int n = r / KP1, k = r % KP1;
            v = (k < FDIM) ? (short)f2bf(Wv1[(size_t)k * HID + n]) : (short)0;
        } else if (idx < WT_WE3) {
            int r = idx - WT_WE2; int n = r / KP2, k = r % KP2;
            v = (short)f2bf(We2[(size_t)k * HID + n]);
        } else if (idx < WT_WH1) {
            int r = idx - WT_WE3; int n = r / KP2, k = r % KP2;
            v = (short)f2bf(We3[(size_t)k * HID + n]);
        } else if (idx < WT_WH2) {
            int r = idx - WT_WH1; int n = r / KN1, k = r % KN1;
            v = (k < 193) ? (short)f2bf(Wh1[(size_t)k * HID + n]) : (short)0;
        } else {
            int r = idx - WT_WH2; int n = r / KP2, k = r % KP2;
            v = (short)f2bf(Wh2[(size_t)k * OUTC + n]);
        }
        wt[idx] = v;
    }
    if (idx < PKP_N) {
        float pv;
        int k = idx >> 7, c = idx & 127;
        switch (k) {
            case 0: pv = be1[c]; break;
            case 1: pv = bv1[c]; break;
            case 2: pv = ge1[c]; break;
            case 3: pv = bte1[c]; break;
            case 4: pv = gv1[c]; break;
            case 5: pv = btv1[c]; break;
            case 6: pv = Wv2[c]; break;
            case 7: pv = be2[c]; break;
            case 8: pv = be3[c]; break;
            default: pv = bv2[0]; break;   // idx == 1152
        }
        pkp[idx] = pv;
    }
    if (idx < NEDGE)
        __hip_atomic_fetch_add(&deg[ei[NEDGE + idx]], 1, __ATOMIC_RELAXED, __HIP_MEMORY_SCOPE_AGENT);
}

// ------------------------------------------------- exclusive scan -> cursor
__global__ __launch_bounds__(1024)
void eg_scan(const int* __restrict__ deg, int* __restrict__ cur)
{
    __shared__ int part[1024];
    const int tid = threadIdx.x;
    const int chunk = (NNODE + 1023) / 1024;   // 20
    const int base = tid * chunk;
    const int lim = min(base + chunk, NNODE);
    int s = 0;
    for (int j = base; j < lim; ++j) s += deg[j];
    part[tid] = s;
    __syncthreads();
    for (int off = 1; off < 1024; off <<= 1) {
        int v = (tid >= off) ? part[tid - off] : 0;
        __syncthreads();
        part[tid] += v;
        __syncthreads();
    }
    int run = (tid > 0) ? part[tid - 1] : 0;
    for (int j = base; j < lim; ++j) { cur[j] = run; run += deg[j]; }
}

// ------------------------------------------------- dst-sorted permutation
__global__ __launch_bounds__(256)
void eg_scatter(const int* __restrict__ ei, int* __restrict__ cur,
                int* __restrict__ perm)
{
    int i = blockIdx.x * 256 + threadIdx.x;
    if (i < NEDGE) {
        int d = ei[NEDGE + i];
        int p = __hip_atomic_fetch_add(&cur[d], 1, __ATOMIC_RELAXED, __HIP_MEMORY_SCOPE_AGENT);
        perm[p] = i;
    }
}

// ---------------------------------------------------------------- edge kernel
// NOTE: 7 blocks/CU (LDS 22 KB) is a measured sharp optimum. 8 blocks/CU
// (R9, aliased cagg, 13.8 KB LDS) thrashes the per-XCD L2: WRITE_SIZE
// 30.6 -> 280 MB, dur 356 -> 406 us. Do not raise residency here.
__global__ __launch_bounds__(256, 7)
void eg_edge(const float* __restrict__ x, const float* __restrict__ pos,
             const float* __restrict__ vel,
             const float* __restrict__ pkp,
             const short* __restrict__ wt,
             const int* __restrict__ ei, const int* __restrict__ perm,
             float* __restrict__ mh, float* __restrict__ mv)
{
    __shared__ __align__(16) short frag_s[5 * 2 * 64 * 8];        // 10240 B
    __shared__ __align__(4) unsigned short cagg_s[TE * CAGS];     // 8320 B
    __shared__ float psum_s[512];                                  // 2048 B
    __shared__ float mu_s[64], rs_s[64];
    __shared__ int   dst_s[TE], src_s[TE];
    __shared__ float rel_s[TE * 2], vw_s[TE];

    const int tid  = threadIdx.x;
    const int lane = tid & 63;
    const int wid  = tid >> 6;
    const int lr   = lane & 15;
    const int quad = lane >> 4;
    const int n0w  = wid * 32;
    // XCD-aware swizzle: XCD (bid & 7) gets a CONTIGUOUS dst-sorted slice,
    // so its mh slice (~1.3 MB) and x[dst] rows stay resident in its 4 MB L2.
    const int bid  = (blockIdx.x & 7) * XSTR + (blockIdx.x >> 3);
    const int e_base = bid * TE;

    const short* We1T = wt + WT_WE1;
    const short* Wv1T = wt + WT_WV1;
    const short* We2T = wt + WT_WE2;
    const short* We3T = wt + WT_WE3;

    // ---- P0: permuted indices + geometry, zero kstep-4 frag region
    float geo[5];
    if (tid < TE) {
        int gi = perm[e_base + tid];
        int eS = ei[gi];
        int eD = ei[NEDGE + gi];
        src_s[tid] = eS; dst_s[tid] = eD;
        float rx = pos[2 * eS]     - pos[2 * eD];
        float ry = pos[2 * eS + 1] - pos[2 * eD + 1];
        float vx = vel[2 * eS]     - vel[2 * eD];
        float vy = vel[2 * eS + 1] - vel[2 * eD + 1];
        float dsq = rx * rx + ry * ry;
        float dvr = vx * rx + vy * ry;
        float r2  = fminf(1.0f / (dsq + 0.05f), 20.0f);
        float r6  = fminf(r2 * r2 * r2, 400.0f);
        float r12 = fminf(r6 * r6, 160000.0f);
        geo[0] = dsq; geo[1] = dvr; geo[2] = r2; geo[3] = r6; geo[4] = r12;
        rel_s[2 * tid] = rx; rel_s[2 * tid + 1] = ry;
    }
    if (tid < 128) {
        int4 z = {0, 0, 0, 0};
        *(int4*)&frag_s[4 * 2 * 64 * 8 + tid * 8] = z;
    }
    __syncthreads();

    // ---- P1: geo + gather x into A1 fragments (packed bf16)
    if (tid < TE) {
        int off = fragOff(4, tid >> 4, (tid & 15));
        #pragma unroll
        for (int j = 0; j < 5; ++j) frag_s[off + j] = (short)f2bf(geo[j]);
    }
    {
        const int e = tid & 31, slot = tid >> 5;
        const int d = dst_s[e], s = src_s[e];
        #pragma unroll
        for (int h = 0; h < 2; ++h) {
            int o = slot + h * 8;
            int node = h ? s : d;
            int c0 = (o & 7) * 8;
            const float4 a0 = *(const float4*)&x[(size_t)node * NCH + c0];
            const float4 a1 = *(const float4*)&x[(size_t)node * NCH + c0 + 4];
            uint4 pk;
            pk.x = f2bf_pk(a0.x, a0.y); pk.y = f2bf_pk(a0.z, a0.w);
            pk.z = f2bf_pk(a1.x, a1.y); pk.w = f2bf_pk(a1.z, a1.w);
            int ks = o >> 2, kq = o & 3;
            *(uint4*)&frag_s[fragOff(ks, e >> 4, kq * 16 + (e & 15))] = pk;
        }
    }
    __syncthreads();

    const int ncol0 = n0w + lr;
    const int ncol1 = n0w + 16 + lr;
    const float* p0 = pkp + ncol0;     // single base, imm offsets k*128
    const float* p1 = pkp + ncol1;

    // ---- P2: dual GEMM1 via MFMA (M=32, N=128, K=160)
    f32x4 zero4 = {0.f, 0.f, 0.f, 0.f};
    f32x4 accE[2][2], accV[2][2];
    #pragma unroll
    for (int mt = 0; mt < 2; ++mt)
        #pragma unroll
        for (int nt = 0; nt < 2; ++nt) { accE[mt][nt] = zero4; accV[mt][nt] = zero4; }
    {
        const short* pa = &frag_s[lane * 8];
        const short* pwE0 = We1T + ncol0 * KP1 + quad * 8;
        const short* pwE1 = We1T + ncol1 * KP1 + quad * 8;
        const short* pwV0 = Wv1T + ncol0 * KP1 + quad * 8;
        const short* pwV1 = Wv1T + ncol1 * KP1 + quad * 8;
        #pragma unroll
        for (int ks = 0; ks < 5; ++ks) {
            bf16x8 af0 = *(const bf16x8*)&pa[ks * 1024];
            bf16x8 af1 = *(const bf16x8*)&pa[ks * 1024 + 512];
            bf16x8 bwE0 = *(const bf16x8*)&pwE0[ks * 32];
            bf16x8 bwE1 = *(const bf16x8*)&pwE1[ks * 32];
            bf16x8 bwV0 = *(const bf16x8*)&pwV0[ks * 32];
            bf16x8 bwV1 = *(const bf16x8*)&pwV1[ks * 32];
            accE[0][0] = __builtin_amdgcn_mfma_f32_16x16x32_bf16(af0, bwE0, accE[0][0], 0, 0, 0);
            accE[1][0] = __builtin_amdgcn_mfma_f32_16x16x32_bf16(af1, bwE0, accE[1][0], 0, 0, 0);
            accE[0][1] = __builtin_amdgcn_mfma_f32_16x16x32_bf16(af0, bwE1, accE[0][1], 0, 0, 0);
            accE[1][1] = __builtin_amdgcn_mfma_f32_16x16x32_bf16(af1, bwE1, accE[1][1], 0, 0, 0);
            accV[0][0] = __builtin_amdgcn_mfma_f32_16x16x32_bf16(af0, bwV0, accV[0][0], 0, 0, 0);
            accV[1][0] = __builtin_amdgcn_mfma_f32_16x16x32_bf16(af1, bwV0, accV[1][0], 0, 0, 0);
            accV[0][1] = __builtin_amdgcn_mfma_f32_16x16x32_bf16(af0, bwV1, accV[0][1], 0, 0, 0);
            accV[1][1] = __builtin_amdgcn_mfma_f32_16x16x32_bf16(af1, bwV1, accV[1][1], 0, 0, 0);
        }
    }
    {
        float be0 = p0[0], be_1 = p1[0];
        float bv0 = p0[128], bv_1 = p1[128];
        #pragma unroll
        for (int mt = 0; mt < 2; ++mt)
            #pragma unroll
            for (int r = 0; r < 4; ++r) {
                accE[mt][0][r] += be0; accE[mt][1][r] += be_1;
                accV[mt][0][r] += bv0; accV[mt][1][r] += bv_1;
            }
    }

    // ---- P3: LN stats in-register (ds_swizzle butterflies, imm patterns)
    #pragma unroll
    for (int mt = 0; mt < 2; ++mt)
        #pragma unroll
        for (int r = 0; r < 4; ++r) {
            float se = accE[mt][0][r] + accE[mt][1][r];
            float qe = accE[mt][0][r] * accE[mt][0][r] + accE[mt][1][r] * accE[mt][1][r];
            float sv = accV[mt][0][r] + accV[mt][1][r];
            float qv = accV[mt][0][r] * accV[mt][0][r] + accV[mt][1][r] * accV[mt][1][r];
            RED16(se); RED16(qe); RED16(sv); RED16(qv);
            if (lr == 0) {
                int row = mt * 16 + quad * 4 + r;
                psum_s[      row * 4 + wid] = se;
                psum_s[128 + row * 4 + wid] = qe;
                psum_s[256 + row * 4 + wid] = sv;
                psum_s[384 + row * 4 + wid] = qv;
            }
        }
    __syncthreads();
    if (tid < 64) {
        int p = tid >> 5, row = tid & 31;
        float s = 0.f, q = 0.f;
        #pragma unroll
        for (int w = 0; w < 4; ++w) {
            s += psum_s[p * 256 +       row * 4 + w];
            q += psum_s[p * 256 + 128 + row * 4 + w];
        }
        float mu = s * (1.0f / HID);
        float var = q * (1.0f / HID) - mu * mu;
        mu_s[p * 32 + row] = mu;
        rs_s[p * 32 + row] = rsqrtf(var + LN_EPS);
    }
    __syncthreads();

    // ---- P4: normalize in-register; E -> A2 frags, V -> vw partials
    {
        float gE0 = p0[256], gE1 = p1[256];
        float tE0 = p0[384], tE1 = p1[384];
        float gV0 = p0[512], gV1 = p1[512];
        float tV0 = p0[640], tV1 = p1[640];
        float w20 = p0[768], w21 = p1[768];
        int ks0 = ncol0 >> 5, kq0 = (ncol0 & 31) >> 3, j0 = ncol0 & 7;
        int ks1 = ncol1 >> 5, kq1 = (ncol1 & 31) >> 3, j1 = ncol1 & 7;
        short* bp0 = &frag_s[(ks0 * 128 + kq0 * 16 + quad * 4) * 8 + j0];
        short* bp1 = &frag_s[(ks1 * 128 + kq1 * 16 + quad * 4) * 8 + j1];
        #pragma unroll
        for (int mt = 0; mt < 2; ++mt)
            #pragma unroll
            for (int r = 0; r < 4; ++r) {
                int rlow = quad * 4 + r, row = mt * 16 + rlow;
                float mu = mu_s[row], rsv = rs_s[row];
                float muV = mu_s[32 + row], rsV = rs_s[32 + row];
                float h0 = sp((accE[mt][0][r] - mu) * rsv * gE0 + tE0);
                float h1 = sp((accE[mt][1][r] - mu) * rsv * gE1 + tE1);
                unsigned int ph = f2bf_pk(h0, h1);
                bp0[mt * 512 + r * 8] = (short)(ph & 0xFFFFu);
                bp1[mt * 512 + r * 8] = (short)(ph >> 16);
                float v0 = sp((accV[mt][0][r] - muV) * rsV * gV0 + tV0);
                float v1 = sp((accV[mt][1][r] - muV) * rsV * gV1 + tV1);
                float vp = v0 * w20 + v1 * w21;
                RED16(vp);
                if (lr == 0) psum_s[row * 4 + wid] = vp;
            }
    }
    __syncthreads();
    if (tid < TE) {
        float s = 0.f;
        #pragma unroll
        for (int w = 0; w < 4; ++w) s += psum_s[tid * 4 + w];
        vw_s[tid] = s + pkp[1152];
    }

    // ---- P5: GEMM2 (M=32, N=128, K=128) + softplus -> A3 fragments
    {
        f32x4 acc2[2][2];
        #pragma unroll
        for (int mt = 0; mt < 2; ++mt)
            #pragma unroll
            for (int nt = 0; nt < 2; ++nt) acc2[mt][nt] = zero4;
        {
            const short* pa = &frag_s[lane * 8];
            const short* pw0 = We2T + ncol0 * KP2 + quad * 8;
            const short* pw1 = We2T + ncol1 * KP2 + quad * 8;
            #pragma unroll
            for (int ks = 0; ks < 4; ++ks) {
                bf16x8 af0 = *(const bf16x8*)&pa[ks * 1024];
                bf16x8 af1 = *(const bf16x8*)&pa[ks * 1024 + 512];
                bf16x8 bw0 = *(const bf16x8*)&pw0[ks * 32];
                bf16x8 bw1 = *(const bf16x8*)&pw1[ks * 32];
                acc2[0][0] = __builtin_amdgcn_mfma_f32_16x16x32_bf16(af0, bw0, acc2[0][0], 0, 0, 0);
                acc2[1][0] = __builtin_amdgcn_mfma_f32_16x16x32_bf16(af1, bw0, acc2[1][0], 0, 0, 0);
                acc2[0][1] = __builtin_amdgcn_mfma_f32_16x16x32_bf16(af0, bw1, acc2[0][1], 0, 0, 0);
                acc2[1][1] = __builtin_amdgcn_mfma_f32_16x16x32_bf16(af1, bw1, acc2[1][1], 0, 0, 0);
            }
        }
        __syncthreads();   // all A2 reads done before overwriting with A3
        float b2a = p0[896], b2b = p1[896];
        int ksA = ncol0 >> 5, kqA = (ncol0 & 31) >> 3, jA = ncol0 & 7;
        int ksB = ncol1 >> 5, kqB = (ncol1 & 31) >> 3, jB = ncol1 & 7;
        short* bpA = &frag_s[(ksA * 128 + kqA * 16 + quad * 4) * 8 + jA];
        short* bpB = &frag_s[(ksB * 128 + kqB * 16 + quad * 4) * 8 + jB];
        #pragma unroll
        for (int mt = 0; mt < 2; ++mt) {
            unsigned int uA0 = f2bf_pk(sp(acc2[mt][0][0] + b2a), sp(acc2[mt][0][1] + b2a));
            unsigned int uA1 = f2bf_pk(sp(acc2[mt][0][2] + b2a), sp(acc2[mt][0][3] + b2a));
            unsigned int uB0 = f2bf_pk(sp(acc2[mt][1][0] + b2b), sp(acc2[mt][1][1] + b2b));
            unsigned int uB1 = f2bf_pk(sp(acc2[mt][1][2] + b2b), sp(acc2[mt][1][3] + b2b));
            bpA[mt * 512 +  0] = (short)(uA0 & 0xFFFFu);
            bpA[mt * 512 +  8] = (short)(uA0 >> 16);
            bpA[mt * 512 + 16] = (short)(uA1 & 0xFFFFu);
            bpA[mt * 512 + 24] = (short)(uA1 >> 16);
            bpB[mt * 512 +  0] = (short)(uB0 & 0xFFFFu);
            bpB[mt * 512 +  8] = (short)(uB0 >> 16);
            bpB[mt * 512 + 16] = (short)(uB1 & 0xFFFFu);
            bpB[mt * 512 + 24] = (short)(uB1 >> 16);
        }
    }
    __syncthreads();

    // ---- P6: GEMM3 (M=32, N=128, K=128) + bias -> bf16 Cagg LDS
    {
        f32x4 acc3[2][2];
        #pragma unroll
        for (int mt = 0; mt < 2; ++mt)
            #pragma unroll
            for (int nt = 0; nt < 2; ++nt) acc3[mt][nt] = zero4;
        {
            const short* pa = &frag_s[lane * 8];
            const short* pw0 = We3T + ncol0 * KP2 + quad * 8;
            const short* pw1 = We3T + ncol1 * KP2 + quad * 8;
            #pragma unroll
            for (int ks = 0; ks < 4; ++ks) {
                bf16x8 af0 = *(const bf16x8*)&pa[ks * 1024];
                bf16x8 af1 = *(const bf16x8*)&pa[ks * 1024 + 512];
                bf16x8 bw0 = *(const bf16x8*)&pw0[ks * 32];
                bf16x8 bw1 = *(const bf16x8*)&pw1[ks * 32];
                acc3[0][0] = __builtin_amdgcn_mfma_f32_16x16x32_bf16(af0, bw0, acc3[0][0], 0, 0, 0);
                acc3[1][0] = __builtin_amdgcn_mfma_f32_16x16x32_bf16(af1, bw0, acc3[1][0], 0, 0, 0);
                acc3[0][1] = __builtin_amdgcn_mfma_f32_16x16x32_bf16(af0, bw1, acc3[0][1], 0, 0, 0);
                acc3[1][1] = __builtin_amdgcn_mfma_f32_16x16x32_bf16(af1, bw1, acc3[1][1], 0, 0, 0);
            }
        }
        float b3a = p0[1024], b3b = p1[1024];
        unsigned short* bpA = &cagg_s[(quad * 4) * CAGS + ncol0];
        unsigned short* bpB = &cagg_s[(quad * 4) * CAGS + ncol1];
        #pragma unroll
        for (int mt = 0; mt < 2; ++mt) {
            unsigned int uA0 = f2bf_pk(acc3[mt][0][0] + b3a, acc3[mt][0][1] + b3a);
            unsigned int uA1 = f2bf_pk(acc3[mt][0][2] + b3a, acc3[mt][0][3] + b3a);
            unsigned int uB0 = f2bf_pk(acc3[mt][1][0] + b3b, acc3[mt][1][1] + b3b);
            unsigned int uB1 = f2bf_pk(acc3[mt][1][2] + b3b, acc3[mt][1][3] + b3b);
            bpA[(mt * 16 + 0) * CAGS] = (unsigned short)(uA0 & 0xFFFFu);
            bpA[(mt * 16 + 1) * CAGS] = (unsigned short)(uA0 >> 16);
            bpA[(mt * 16 + 2) * CAGS] = (unsigned short)(uA1 & 0xFFFFu);
            bpA[(mt * 16 + 3) * CAGS] = (unsigned short)(uA1 >> 16);
            bpB[(mt * 16 + 0) * CAGS] = (unsigned short)(uB0 & 0xFFFFu);
            bpB[(mt * 16 + 1) * CAGS] = (unsigned short)(uB0 >> 16);
            bpB[(mt * 16 + 2) * CAGS] = (unsigned short)(uB1 & 0xFFFFu);
            bpB[(mt * 16 + 3) * CAGS] = (unsigned short)(uB1 >> 16);
        }
    }
    __syncthreads();

    // ---- P7: dst-run segmented atomic flush (rows sorted by dst)
    {
        const int c = tid & 127, h = tid >> 7;
        const unsigned short* cp = &cagg_s[(h * 16) * CAGS + c];
        const int m0 = h * 16;
        float run = bfu2f(cp[0]);
        int curd = dst_s[m0];
        #pragma unroll
        for (int m = 1; m < 16; ++m) {
            int d = dst_s[m0 + m];
            float v = bfu2f(cp[m * CAGS]);
            if (d == curd) run += v;
            else { atomAddF(&mh[(size_t)curd * HID + c], run); curd = d; run = v; }
        }
        atomAddF(&mh[(size_t)curd * HID + c], run);
    }
    // ---- P8: m_v segmented flush
    if (tid < 2) {
        const int c = tid;
        float run = vw_s[0] * rel_s[c];
        int curd = dst_s[0];
        for (int m = 1; m < TE; ++m) {
            int d = dst_s[m];
            float v = vw_s[m] * rel_s[2 * m + c];
            if (d == curd) run += v;
            else { atomAddF(&mv[2 * curd + c], run); curd = d; run = v; }
        }
        atomAddF(&mv[2 * curd + c], run);
    }
}

// ---------------------------------------------------------------- node kernel (MFMA)
__global__ __launch_bounds__(256, 7)
void eg_node(const float* __restrict__ x,
             const float* __restrict__ bh1, const float* __restrict__ gh1,
             const float* __restrict__ bth1, const float* __restrict__ bh2,
             const float* __restrict__ mh, const float* __restrict__ mv,
             const int* __restrict__ deg, const short* __restrict__ wt,
             float* __restrict__ out)
{
    __shared__ __align__(16) short frag_s[7 * 2 * 64 * 8];   // 14336 B
    __shared__ float psum_s[256];
    __shared__ float mu_s[32], rs_s[32];
    __shared__ float rden_s[TN], norm_s[TN];

    const int tid  = threadIdx.x;
    const int lane = tid & 63;
    const int wid  = tid >> 6;
    const int lr   = lane & 15;
    const int quad = lane >> 4;
    const int n0w  = wid * 32;
    const int n_base = blockIdx.x * TN;

    const short* Wh1T = wt + WT_WH1;
    const short* Wh2T = wt + WT_WH2;

    if (tid < TN) {
        int n = n_base + tid;
        float den = fmaxf((float)deg[n], 1.0f);
        float rd = 1.0f / den;
        float ax = mv[2 * n] * rd + 1e-8f;
        float ay = mv[2 * n + 1] * rd + 1e-8f;
        rden_s[tid] = rd;
        norm_s[tid] = sqrtf(ax * ax + ay * ay);
    }
    if (tid < 128) {
        int4 z = {0, 0, 0, 0};
        *(int4*)&frag_s[6 * 2 * 64 * 8 + tid * 8] = z;
    }
    __syncthreads();

    {
        const int e = tid & 31, slot = tid >> 5;
        const int n = n_base + e;
        {
            int c0 = slot * 8;
            const float4 a0 = *(const float4*)&x[(size_t)n * NCH + c0];
            const float4 a1 = *(const float4*)&x[(size_t)n * NCH + c0 + 4];
            uint4 pk;
            pk.x = f2bf_pk(a0.x, a0.y); pk.y = f2bf_pk(a0.z, a0.w);
            pk.z = f2bf_pk(a1.x, a1.y); pk.w = f2bf_pk(a1.z, a1.w);
            int ks = slot >> 2, kq = slot & 3;
            *(uint4*)&frag_s[fragOff(ks, e >> 4, kq * 16 + (e & 15))] = pk;
        }
        float rd = rden_s[e];
        #pragma unroll
        for (int h = 0; h < 2; ++h) {
            int o = 8 + slot + h * 8;
            int k0 = (o - 8) * 8;
            const float4 a0 = *(const float4*)&mh[(size_t)n * HID + k0];
            const float4 a1 = *(const float4*)&mh[(size_t)n * HID + k0 + 4];
            uint4 pk;
            pk.x = f2bf_pk(a0.x * rd, a0.y * rd); pk.y = f2bf_pk(a0.z * rd, a0.w * rd);
            pk.z = f2bf_pk(a1.x * rd, a1.y * rd); pk.w = f2bf_pk(a1.z * rd, a1.w * rd);
            int ks = o >> 2, kq = o & 3;
            *(uint4*)&frag_s[fragOff(ks, e >> 4, kq * 16 + (e & 15))] = pk;
        }
    }
    if (tid < TN) {
        frag_s[fragOff(6, tid >> 4, (tid & 15))] = (short)f2bf(norm_s[tid]);
    }
    __syncthreads();

    const int ncol0 = n0w + lr;
    const int ncol1 = n0w + 16 + lr;

    f32x4 zero4 = {0.f, 0.f, 0.f, 0.f};
    f32x4 acc1[2][2];
    #pragma unroll
    for (int mt = 0; mt < 2; ++mt)
        #pragma unroll
        for (int nt = 0; nt < 2; ++nt) acc1[mt][nt] = zero4;
    {
        const short* pa = &frag_s[lane * 8];
        const short* pw0 = Wh1T + ncol0 * KN1 + quad * 8;
        const short* pw1 = Wh1T + ncol1 * KN1 + quad * 8;
        #pragma unroll
        for (int ks = 0; ks < 7; ++ks) {
            bf16x8 af0 = *(const bf16x8*)&pa[ks * 1024];
            bf16x8 af1 = *(const bf16x8*)&pa[ks * 1024 + 512];
            bf16x8 bw0 = *(const bf16x8*)&pw0[ks * 32];
            bf16x8 bw1 = *(const bf16x8*)&pw1[ks * 32];
            acc1[0][0] = __builtin_amdgcn_mfma_f32_16x16x32_bf16(af0, bw0, acc1[0][0], 0, 0, 0);
            acc1[1][0] = __builtin_amdgcn_mfma_f32_16x16x32_bf16(af1, bw0, acc1[1][0], 0, 0, 0);
            acc1[0][1] = __builtin_amdgcn_mfma_f32_16x16x32_bf16(af0, bw1, acc1[0][1], 0, 0, 0);
            acc1[1][1] = __builtin_amdgcn_mfma_f32_16x16x32_bf16(af1, bw1, acc1[1][1], 0, 0, 0);
        }
    }
    {
        float b0 = bh1[ncol0], b1 = bh1[ncol1];
        #pragma unroll
        for (int mt = 0; mt < 2; ++mt)
            #pragma unroll
            for (int r = 0; r < 4; ++r) { acc1[mt][0][r] += b0; acc1[mt][1][r] += b1; }
    }

    #pragma unroll
    for (int mt = 0; mt < 2; ++mt)
        #pragma unroll
        for (int r = 0; r < 4; ++r) {
            float s = acc1[mt][0][r] + acc1[mt][1][r];
            float q = acc1[mt][0][r] * acc1[mt][0][r] + acc1[mt][1][r] * acc1[mt][1][r];
            RED16(s); RED16(q);
            if (lr == 0) {
                int row = mt * 16 + quad * 4 + r;
                psum_s[row * 4 + wid]       = s;
                psum_s[128 + row * 4 + wid] = q;
            }
        }
    __syncthreads();
    if (tid < 32) {
        float s = 0.f, q = 0.f;
        #pragma unroll
        for (int w = 0; w < 4; ++w) {
            s += psum_s[tid * 4 + w];
            q += psum_s[128 + tid * 4 + w];
        }
        float mu = s * (1.0f / HID);
        float var = q * (1.0f / HID) - mu * mu;
        mu_s[tid] = mu;
        rs_s[tid] = rsqrtf(var + LN_EPS);
    }
    __syncthreads();

    {
        float g0 = gh1[ncol0], g1 = gh1[ncol1];
        float t0 = bth1[ncol0], t1 = bth1[ncol1];
        int ks0 = ncol0 >> 5, kq0 = (ncol0 & 31) >> 3, j0 = ncol0 & 7;
        int ks1 = ncol1 >> 5, kq1 = (ncol1 & 31) >> 3, j1 = ncol1 & 7;
        short* bp0 = &frag_s[(ks0 * 128 + kq0 * 16 + quad * 4) * 8 + j0];
        short* bp1 = &frag_s[(ks1 * 128 + kq1 * 16 + quad * 4) * 8 + j1];
        #pragma unroll
        for (int mt = 0; mt < 2; ++mt)
            #pragma unroll
            for (int r = 0; r < 4; ++r) {
                int row = mt * 16 + quad * 4 + r;
                float mu = mu_s[row], rsv = rs_s[row];
                float h0 = sp((acc1[mt][0][r] - mu) * rsv * g0 + t0);
                float h1 = sp((acc1[mt][1][r] - mu) * rsv * g1 + t1);
                unsigned int ph = f2bf_pk(h0, h1);
                bp0[mt * 512 + r * 8] = (short)(ph & 0xFFFFu);
                bp1[mt * 512 + r * 8] = (short)(ph >> 16);
            }
    }
    __syncthreads();

    {
        const int col = wid * 16 + lr;
        f32x4 acc2[2] = { zero4, zero4 };
        const short* pa = &frag_s[lane * 8];
        const short* pw = Wh2T + col * KP2 + quad * 8;
        #pragma unroll
        for (int ks = 0; ks < 4; ++ks) {
            bf16x8 af0 = *(const bf16x8*)&pa[ks * 1024];
            bf16x8 af1 = *(const bf16x8*)&pa[ks * 1024 + 512];
            bf16x8 bw = *(const bf16x8*)&pw[ks * 32];
            acc2[0] = __builtin_amdgcn_mfma_f32_16x16x32_bf16(af0, bw, acc2[0], 0, 0, 0);
            acc2[1] = __builtin_amdgcn_mfma_f32_16x16x32_bf16(af1, bw, acc2[1], 0, 0, 0);
        }
        float bo = bh2[col];
        #pragma unroll
        for (int mt = 0; mt < 2; ++mt)
            #pragma unroll
            for (int r = 0; r < 4; ++r) {
                int m = mt * 16 + quad * 4 + r;
                size_t idx = (size_t)(n_base + m) * OUTC + col;
                out[idx] = x[(size_t)(n_base + m) * NCH + col] + acc2[mt][r] + bo;
            }
    }
}

// ---------------------------------------------------------------- launch
extern "C" void kernel_launch(void* const* d_in, const int* in_sizes, int n_in,
                              void* d_out, int out_size, void* d_ws, size_t ws_size,
                              hipStream_t stream)
{
    const float* x    = (const float*)d_in[0];
    const float* pos  = (const float*)d_in[1];
    const float* vel  = (const float*)d_in[2];
    const float* We1  = (const float*)d_in[3];
    const float* be1  = (const float*)d_in[4];
    const float* ge1  = (const float*)d_in[5];
    const float* bte1 = (const float*)d_in[6];
    const float* We2  = (const float*)d_in[7];
    const float* be2  = (const float*)d_in[8];
    const float* We3  = (const float*)d_in[9];
    const float* be3  = (const float*)d_in[10];
    const float* Wv1  = (const float*)d_in[11];
    const float* bv1  = (const float*)d_in[12];
    const float* gv1  = (const float*)d_in[13];
    const float* btv1 = (const float*)d_in[14];
    const float* Wv2  = (const float*)d_in[15];
    const float* bv2  = (const float*)d_in[16];
    const float* Wh1  = (const float*)d_in[17];
    const float* bh1  = (const float*)d_in[18];
    const float* gh1  = (const float*)d_in[19];
    const float* bth1 = (const float*)d_in[20];
    const float* Wh2  = (const float*)d_in[21];
    const float* bh2  = (const float*)d_in[22];
    const int*   ei   = (const int*)d_in[23];

    // workspace layout
    float* mh   = (float*)d_ws;                      // 2,560,000 f
    float* mv   = mh + (size_t)NNODE * HID;          // 40,000 f
    int*   deg  = (int*)(mv + NNODE * 2);            // 20,000 i
    int*   cur  = deg + NNODE;                       // 20,000 i
    int*   perm = cur + NNODE;                       // 640,000 i
    float* pkp  = (float*)(perm + NEDGE);            // 1,280 f
    short* wt   = (short*)(pkp + 1280);              // 110,592 s

    // zero mh, mv, deg (contiguous)
    size_t zbytes = ((size_t)NNODE * HID + NNODE * 2 + NNODE) * sizeof(float);
    hipMemsetAsync(d_ws, 0, zbytes, stream);

    eg_prep<<<dim3(NEDGE / 256), dim3(256), 0, stream>>>(
        We1, Wv1, We2, We3, Wh1, Wh2,
        be1, bv1, ge1, bte1, gv1, btv1, Wv2, be2, be3, bv2,
        ei, wt, pkp, deg);
    eg_scan<<<dim3(1), dim3(1024), 0, stream>>>(deg, cur);
    eg_scatter<<<dim3(NEDGE / 256), dim3(256), 0, stream>>>(ei, cur, perm);

    eg_edge<<<dim3(NEBLK), dim3(256), 0, stream>>>(
        x, pos, vel, pkp, wt, ei, perm, mh, mv);

    eg_node<<<dim3(NNODE / TN), dim3(256), 0, stream>>>(
        x, bh1, gh1, bth1, bh2, mh, mv, deg, wt, (float*)d_out);
}

// Round 11
// 516.754 us; speedup vs baseline: 1.1135x; 1.0072x over previous
//
#include <hip/hip_runtime.h>
#include <stdint.h>

#define NCH    64
#define HID    128
#define OUTC   64
#define NNODE  20000
#define NEDGE  640000
#define FDIM   133
#define TE     32
#define TN     32
#define LN_EPS 1e-5f
#define KP1    160          // K of edge GEMM1, padded (133 -> 160 = 5*32)
#define KP2    128          // K of edge GEMM2/3
#define KN1    224          // K of node GEMM1, padded (193 -> 224 = 7*32)
#define CAGS   130          // bf16 Cagg LDS row stride (shorts)
#define NEBLK  (NEDGE / TE) // 20000 edge blocks
#define XSTR   (NEBLK / 8)  // 2500 blocks per XCD slice

typedef __attribute__((ext_vector_type(8))) short bf16x8;
typedef __attribute__((ext_vector_type(4))) float f32x4;

__device__ __forceinline__ unsigned short f2bf(float f) {
    union { float f; unsigned int i; } v; v.f = f;
    unsigned int b = v.i;
    return (unsigned short)((b + 0x7FFFu + ((b >> 16) & 1u)) >> 16);
}
#if defined(__has_builtin)
#if __has_builtin(__builtin_amdgcn_cvt_pk_bf16_f32)
#define HAVE_PK_BF16 1
#endif
#endif
__device__ __forceinline__ unsigned int f2bf_pk(float a, float b) {
#ifdef HAVE_PK_BF16
    auto r = __builtin_amdgcn_cvt_pk_bf16_f32(a, b);
    return __builtin_bit_cast(unsigned int, r);
#else
    return (unsigned int)f2bf(a) | ((unsigned int)f2bf(b) << 16);
#endif
}
__device__ __forceinline__ float bfu2f(unsigned short u) {
    union { unsigned int i; float f; } v; v.i = ((unsigned int)u) << 16; return v.f;
}
// fast softplus: hardware v_exp_f32 / v_log_f32
__device__ __forceinline__ float sp(float xv) {
    return fmaxf(xv, 0.f) + __logf(1.0f + __expf(-fabsf(xv)));
}
__device__ __forceinline__ void atomAddF(float* p, float v) {
    __hip_atomic_fetch_add(p, v, __ATOMIC_RELAXED, __HIP_MEMORY_SCOPE_AGENT);
}
// xor-butterfly via ds_swizzle with immediate pattern (no lane math)
template<int PAT> __device__ __forceinline__ float shx(float v) {
    int i = __builtin_amdgcn_ds_swizzle(__builtin_bit_cast(int, v), PAT);
    return __builtin_bit_cast(float, i);
}
#define RED16(v) { v += shx<0x041F>(v); v += shx<0x081F>(v); v += shx<0x101F>(v); v += shx<0x201F>(v); }

// A/B fragment offset in a [kstep][mtile(2)][lane(64)][8] bf16 buffer
__device__ __forceinline__ int fragOff(int ks, int mt, int lanepos) {
    return ((ks * 2 + mt) * 64 + lanepos) * 8;
}

#define WT_WE1 0
#define WT_WV1 (128 * KP1)
#define WT_WE2 (2 * 128 * KP1)
#define WT_WE3 (2 * 128 * KP1 + 128 * KP2)
#define WT_WH1 (2 * 128 * KP1 + 2 * 128 * KP2)            // 73728
#define WT_WH2 (WT_WH1 + 128 * KN1)                        // +28672
#define WT_TOTAL (WT_WH2 + 64 * KP2)                       // 110592 shorts
#define PKP_N  1153                                        // packed param floats

// ---- fused: zero mh/mv + weight transpose + param pack + degree histogram
// (deg is zeroed by a small 80 KB memset BEFORE this kernel — the histogram
//  atomics here race against any in-kernel deg zeroing, so deg must be
//  pre-zeroed externally.)
__global__ __launch_bounds__(256)
void eg_prep(const float* __restrict__ We1, const float* __restrict__ Wv1,
             const float* __restrict__ We2, const float* __restrict__ We3,
             const float* __restrict__ Wh1, const float* __restrict__ Wh2,
             const float* __restrict__ be1, const float* __restrict__ bv1,
             const float* __restrict__ ge1, const float* __restrict__ bte1,
             const float* __restrict__ gv1, const float* __restrict__ btv1,
             const float* __restrict__ Wv2, const float* __restrict__ be2,
             const float* __restrict__ be3, const float* __restrict__ bv2,
             const int* __restrict__ ei,
             short* __restrict__ wt, float* __restrict__ pkp,
             int* __restrict__ deg, float* __restrict__ mhz)
{
    int idx = blockIdx.x * 256 + threadIdx.x;   // 0 .. 639999
    // zero mh (2.56M f) + mv (40k f) = 650,000 float4
    {
        float4 z = {0.f, 0.f, 0.f, 0.f};
        ((float4*)mhz)[idx] = z;
        if (idx < 10000) ((float4*)mhz)[640000 + idx] = z;
    }
    if (idx < WT_TOTAL) {
        short v;
        if (idx < WT_WV1) {
            int n = idx / KP1, k = idx % KP1;
            v = (k < FDIM) ? (short)f2bf(We1[(size_t)k * HID + n]) : (short)0;
        } else if (idx < WT_WE2) {
            int r = idx - WT_WV1; int n = r / KP1, k = r % KP1;
            v = (k < FDIM) ? (short)f2bf(Wv1[(size_t)k * HID + n]) : (short)0;
        } else if (idx < WT_WE3) {
            int r = idx - WT_WE2; int n = r / KP2, k = r % KP2;
            v = (short)f2bf(We2[(size_t)k * HID + n]);
        } else if (idx < WT_WH1) {
            int r = idx - WT_WE3; int n = r / KP2, k = r % KP2;
            v = (short)f2bf(We3[(size_t)k * HID + n]);
        } else if (idx < WT_WH2) {
            int r = idx - WT_WH1; int n = r / KN1, k = r % KN1;
            v = (k < 193) ? (short)f2bf(Wh1[(size_t)k * HID + n]) : (short)0;
        } else {
            int r = idx - WT_WH2; int n = r / KP2, k = r % KP2;
            v = (short)f2bf(Wh2[(size_t)k * OUTC + n]);
        }
        wt[idx] = v;
    }
    if (idx < PKP_N) {
        float pv;
        int k = idx >> 7, c = idx & 127;
        switch (k) {
            case 0: pv = be1[c]; break;
            case 1: pv = bv1[c]; break;
            case 2: pv = ge1[c]; break;
            case 3: pv = bte1[c]; break;
            case 4: pv = gv1[c]; break;
            case 5: pv = btv1[c]; break;
            case 6: pv = Wv2[c]; break;
            case 7: pv = be2[c]; break;
            case 8: pv = be3[c]; break;
            default: pv = bv2[0]; break;   // idx == 1152
        }
        pkp[idx] = pv;
    }
    if (idx < NEDGE)
        __hip_atomic_fetch_add(&deg[ei[NEDGE + idx]], 1, __ATOMIC_RELAXED, __HIP_MEMORY_SCOPE_AGENT);
}

// ------------------------------------------------- exclusive scan -> cursor
__global__ __launch_bounds__(1024)
void eg_scan(const int* __restrict__ deg, int* __restrict__ cur)
{
    __shared__ int part[1024];
    const int tid = threadIdx.x;
    const int chunk = (NNODE + 1023) / 1024;   // 20
    const int base = tid * chunk;
    const int lim = min(base + chunk, NNODE);
    int s = 0;
    for (int j = base; j < lim; ++j) s += deg[j];
    part[tid] = s;
    __syncthreads();
    for (int off = 1; off < 1024; off <<= 1) {
        int v = (tid >= off) ? part[tid - off] : 0;
        __syncthreads();
        part[tid] += v;
        __syncthreads();
    }
    int run = (tid > 0) ? part[tid - 1] : 0;
    for (int j = base; j < lim; ++j) { cur[j] = run; run += deg[j]; }
}

// ------------------------------------------------- dst-sorted permutation
__global__ __launch_bounds__(256)
void eg_scatter(const int* __restrict__ ei, int* __restrict__ cur,
                int* __restrict__ perm)
{
    int i = blockIdx.x * 256 + threadIdx.x;
    if (i < NEDGE) {
        int d = ei[NEDGE + i];
        int p = __hip_atomic_fetch_add(&cur[d], 1, __ATOMIC_RELAXED, __HIP_MEMORY_SCOPE_AGENT);
        perm[p] = i;
    }
}

// ---------------------------------------------------------------- edge kernel
// NOTE: 7 blocks/CU (LDS 22 KB) is a measured sharp optimum. 8 blocks/CU
// (R9, aliased cagg, 13.8 KB LDS) thrashes the per-XCD L2: WRITE_SIZE
// 30.6 -> 280 MB, dur 356 -> 406 us. Do not raise residency here.
__global__ __launch_bounds__(256, 7)
void eg_edge(const float* __restrict__ x, const float* __restrict__ pos,
             const float* __restrict__ vel,
             const float* __restrict__ pkp,
             const short* __restrict__ wt,
             const int* __restrict__ ei, const int* __restrict__ perm,
             float* __restrict__ mh, float* __restrict__ mv)
{
    __shared__ __align__(16) short frag_s[5 * 2 * 64 * 8];        // 10240 B
    __shared__ __align__(4) unsigned short cagg_s[TE * CAGS];     // 8320 B
    __shared__ float psum_s[512];                                  // 2048 B
    __shared__ float mu_s[64], rs_s[64];
    __shared__ int   dst_s[TE], src_s[TE];
    __shared__ float rel_s[TE * 2], vw_s[TE];

    const int tid  = threadIdx.x;
    const int lane = tid & 63;
    const int wid  = tid >> 6;
    const int lr   = lane & 15;
    const int quad = lane >> 4;
    const int n0w  = wid * 32;
    // XCD-aware swizzle: XCD (bid & 7) gets a CONTIGUOUS dst-sorted slice,
    // so its mh slice (~1.3 MB) and x[dst] rows stay resident in its 4 MB L2.
    const int bid  = (blockIdx.x & 7) * XSTR + (blockIdx.x >> 3);
    const int e_base = bid * TE;

    const short* We1T = wt + WT_WE1;
    const short* Wv1T = wt + WT_WV1;
    const short* We2T = wt + WT_WE2;
    const short* We3T = wt + WT_WE3;

    // ---- P0: permuted indices + geometry, zero kstep-4 frag region
    float geo[5];
    if (tid < TE) {
        int gi = perm[e_base + tid];
        int eS = ei[gi];
        int eD = ei[NEDGE + gi];
        src_s[tid] = eS; dst_s[tid] = eD;
        float rx = pos[2 * eS]     - pos[2 * eD];
        float ry = pos[2 * eS + 1] - pos[2 * eD + 1];
        float vx = vel[2 * eS]     - vel[2 * eD];
        float vy = vel[2 * eS + 1] - vel[2 * eD + 1];
        float dsq = rx * rx + ry * ry;
        float dvr = vx * rx + vy * ry;
        float r2  = fminf(1.0f / (dsq + 0.05f), 20.0f);
        float r6  = fminf(r2 * r2 * r2, 400.0f);
        float r12 = fminf(r6 * r6, 160000.0f);
        geo[0] = dsq; geo[1] = dvr; geo[2] = r2; geo[3] = r6; geo[4] = r12;
        rel_s[2 * tid] = rx; rel_s[2 * tid + 1] = ry;
    }
    if (tid < 128) {
        int4 z = {0, 0, 0, 0};
        *(int4*)&frag_s[4 * 2 * 64 * 8 + tid * 8] = z;
    }
    __syncthreads();

    // ---- P1: geo + gather x into A1 fragments (packed bf16)
    if (tid < TE) {
        int off = fragOff(4, tid >> 4, (tid & 15));
        #pragma unroll
        for (int j = 0; j < 5; ++j) frag_s[off + j] = (short)f2bf(geo[j]);
    }
    {
        const int e = tid & 31, slot = tid >> 5;
        const int d = dst_s[e], s = src_s[e];
        #pragma unroll
        for (int h = 0; h < 2; ++h) {
            int o = slot + h * 8;
            int node = h ? s : d;
            int c0 = (o & 7) * 8;
            const float4 a0 = *(const float4*)&x[(size_t)node * NCH + c0];
            const float4 a1 = *(const float4*)&x[(size_t)node * NCH + c0 + 4];
            uint4 pk;
            pk.x = f2bf_pk(a0.x, a0.y); pk.y = f2bf_pk(a0.z, a0.w);
            pk.z = f2bf_pk(a1.x, a1.y); pk.w = f2bf_pk(a1.z, a1.w);
            int ks = o >> 2, kq = o & 3;
            *(uint4*)&frag_s[fragOff(ks, e >> 4, kq * 16 + (e & 15))] = pk;
        }
    }
    __syncthreads();

    const int ncol0 = n0w + lr;
    const int ncol1 = n0w + 16 + lr;
    const float* p0 = pkp + ncol0;     // single base, imm offsets k*128
    const float* p1 = pkp + ncol1;

    // ---- P2: dual GEMM1 via MFMA (M=32, N=128, K=160)
    f32x4 zero4 = {0.f, 0.f, 0.f, 0.f};
    f32x4 accE[2][2], accV[2][2];
    #pragma unroll
    for (int mt = 0; mt < 2; ++mt)
        #pragma unroll
        for (int nt = 0; nt < 2; ++nt) { accE[mt][nt] = zero4; accV[mt][nt] = zero4; }
    {
        const short* pa = &frag_s[lane * 8];
        const short* pwE0 = We1T + ncol0 * KP1 + quad * 8;
        const short* pwE1 = We1T + ncol1 * KP1 + quad * 8;
        const short* pwV0 = Wv1T + ncol0 * KP1 + quad * 8;
        const short* pwV1 = Wv1T + ncol1 * KP1 + quad * 8;
        #pragma unroll
        for (int ks = 0; ks < 5; ++ks) {
            bf16x8 af0 = *(const bf16x8*)&pa[ks * 1024];
            bf16x8 af1 = *(const bf16x8*)&pa[ks * 1024 + 512];
            bf16x8 bwE0 = *(const bf16x8*)&pwE0[ks * 32];
            bf16x8 bwE1 = *(const bf16x8*)&pwE1[ks * 32];
            bf16x8 bwV0 = *(const bf16x8*)&pwV0[ks * 32];
            bf16x8 bwV1 = *(const bf16x8*)&pwV1[ks * 32];
            accE[0][0] = __builtin_amdgcn_mfma_f32_16x16x32_bf16(af0, bwE0, accE[0][0], 0, 0, 0);
            accE[1][0] = __builtin_amdgcn_mfma_f32_16x16x32_bf16(af1, bwE0, accE[1][0], 0, 0, 0);
            accE[0][1] = __builtin_amdgcn_mfma_f32_16x16x32_bf16(af0, bwE1, accE[0][1], 0, 0, 0);
            accE[1][1] = __builtin_amdgcn_mfma_f32_16x16x32_bf16(af1, bwE1, accE[1][1], 0, 0, 0);
            accV[0][0] = __builtin_amdgcn_mfma_f32_16x16x32_bf16(af0, bwV0, accV[0][0], 0, 0, 0);
            accV[1][0] = __builtin_amdgcn_mfma_f32_16x16x32_bf16(af1, bwV0, accV[1][0], 0, 0, 0);
            accV[0][1] = __builtin_amdgcn_mfma_f32_16x16x32_bf16(af0, bwV1, accV[0][1], 0, 0, 0);
            accV[1][1] = __builtin_amdgcn_mfma_f32_16x16x32_bf16(af1, bwV1, accV[1][1], 0, 0, 0);
        }
    }
    {
        float be0 = p0[0], be_1 = p1[0];
        float bv0 = p0[128], bv_1 = p1[128];
        #pragma unroll
        for (int mt = 0; mt < 2; ++mt)
            #pragma unroll
            for (int r = 0; r < 4; ++r) {
                accE[mt][0][r] += be0; accE[mt][1][r] += be_1;
                accV[mt][0][r] += bv0; accV[mt][1][r] += bv_1;
            }
    }

    // ---- P3: LN stats in-register (ds_swizzle butterflies, imm patterns)
    #pragma unroll
    for (int mt = 0; mt < 2; ++mt)
        #pragma unroll
        for (int r = 0; r < 4; ++r) {
            float se = accE[mt][0][r] + accE[mt][1][r];
            float qe = accE[mt][0][r] * accE[mt][0][r] + accE[mt][1][r] * accE[mt][1][r];
            float sv = accV[mt][0][r] + accV[mt][1][r];
            float qv = accV[mt][0][r] * accV[mt][0][r] + accV[mt][1][r] * accV[mt][1][r];
            RED16(se); RED16(qe); RED16(sv); RED16(qv);
            if (lr == 0) {
                int row = mt * 16 + quad * 4 + r;
                psum_s[      row * 4 + wid] = se;
                psum_s[128 + row * 4 + wid] = qe;
                psum_s[256 + row * 4 + wid] = sv;
                psum_s[384 + row * 4 + wid] = qv;
            }
        }
    __syncthreads();
    if (tid < 64) {
        int p = tid >> 5, row = tid & 31;
        float s = 0.f, q = 0.f;
        #pragma unroll
        for (int w = 0; w < 4; ++w) {
            s += psum_s[p * 256 +       row * 4 + w];
            q += psum_s[p * 256 + 128 + row * 4 + w];
        }
        float mu = s * (1.0f / HID);
        float var = q * (1.0f / HID) - mu * mu;
        mu_s[p * 32 + row] = mu;
        rs_s[p * 32 + row] = rsqrtf(var + LN_EPS);
    }
    __syncthreads();

    // ---- P4: normalize in-register; E -> A2 frags, V -> vw partials
    {
        float gE0 = p0[256], gE1 = p1[256];
        float tE0 = p0[384], tE1 = p1[384];
        float gV0 = p0[512], gV1 = p1[512];
        float tV0 = p0[640], tV1 = p1[640];
        float w20 = p0[768], w21 = p1[768];
        int ks0 = ncol0 >> 5, kq0 = (ncol0 & 31) >> 3, j0 = ncol0 & 7;
        int ks1 = ncol1 >> 5, kq1 = (ncol1 & 31) >> 3, j1 = ncol1 & 7;
        short* bp0 = &frag_s[(ks0 * 128 + kq0 * 16 + quad * 4) * 8 + j0];
        short* bp1 = &frag_s[(ks1 * 128 + kq1 * 16 + quad * 4) * 8 + j1];
        #pragma unroll
        for (int mt = 0; mt < 2; ++mt)
            #pragma unroll
            for (int r = 0; r < 4; ++r) {
                int rlow = quad * 4 + r, row = mt * 16 + rlow;
                float mu = mu_s[row], rsv = rs_s[row];
                float muV = mu_s[32 + row], rsV = rs_s[32 + row];
                float h0 = sp((accE[mt][0][r] - mu) * rsv * gE0 + tE0);
                float h1 = sp((accE[mt][1][r] - mu) * rsv * gE1 + tE1);
                bp0[mt * 512 + r * 8] = (short)f2bf(h0);
                bp1[mt * 512 + r * 8] = (short)f2bf(h1);
                float v0 = sp((accV[mt][0][r] - muV) * rsV * gV0 + tV0);
                float v1 = sp((accV[mt][1][r] - muV) * rsV * gV1 + tV1);
                float vp = v0 * w20 + v1 * w21;
                RED16(vp);
                if (lr == 0) psum_s[row * 4 + wid] = vp;
            }
    }
    __syncthreads();
    if (tid < TE) {
        float s = 0.f;
        #pragma unroll
        for (int w = 0; w < 4; ++w) s += psum_s[tid * 4 + w];
        vw_s[tid] = s + pkp[1152];
    }

    // ---- P5: GEMM2 (M=32, N=128, K=128) + softplus -> A3 fragments
    {
        f32x4 acc2[2][2];
        #pragma unroll
        for (int mt = 0; mt < 2; ++mt)
            #pragma unroll
            for (int nt = 0; nt < 2; ++nt) acc2[mt][nt] = zero4;
        {
            const short* pa = &frag_s[lane * 8];
            const short* pw0 = We2T + ncol0 * KP2 + quad * 8;
            const short* pw1 = We2T + ncol1 * KP2 + quad * 8;
            #pragma unroll
            for (int ks = 0; ks < 4; ++ks) {
                bf16x8 af0 = *(const bf16x8*)&pa[ks * 1024];
                bf16x8 af1 = *(const bf16x8*)&pa[ks * 1024 + 512];
                bf16x8 bw0 = *(const bf16x8*)&pw0[ks * 32];
                bf16x8 bw1 = *(const bf16x8*)&pw1[ks * 32];
                acc2[0][0] = __builtin_amdgcn_mfma_f32_16x16x32_bf16(af0, bw0, acc2[0][0], 0, 0, 0);
                acc2[1][0] = __builtin_amdgcn_mfma_f32_16x16x32_bf16(af1, bw0, acc2[1][0], 0, 0, 0);
                acc2[0][1] = __builtin_amdgcn_mfma_f32_16x16x32_bf16(af0, bw1, acc2[0][1], 0, 0, 0);
                acc2[1][1] = __builtin_amdgcn_mfma_f32_16x16x32_bf16(af1, bw1, acc2[1][1], 0, 0, 0);
            }
        }
        __syncthreads();   // all A2 reads done before overwriting with A3
        float b2a = p0[896], b2b = p1[896];
        int ksA = ncol0 >> 5, kqA = (ncol0 & 31) >> 3, jA = ncol0 & 7;
        int ksB = ncol1 >> 5, kqB = (ncol1 & 31) >> 3, jB = ncol1 & 7;
        short* bpA = &frag_s[(ksA * 128 + kqA * 16 + quad * 4) * 8 + jA];
        short* bpB = &frag_s[(ksB * 128 + kqB * 16 + quad * 4) * 8 + jB];
        #pragma unroll
        for (int mt = 0; mt < 2; ++mt)
            #pragma unroll
            for (int r = 0; r < 4; ++r) {
                bpA[mt * 512 + r * 8] = (short)f2bf(sp(acc2[mt][0][r] + b2a));
                bpB[mt * 512 + r * 8] = (short)f2bf(sp(acc2[mt][1][r] + b2b));
            }
    }
    __syncthreads();

    // ---- P6: GEMM3 (M=32, N=128, K=128) + bias -> bf16 Cagg LDS
    {
        f32x4 acc3[2][2];
        #pragma unroll
        for (int mt = 0; mt < 2; ++mt)
            #pragma unroll
            for (int nt = 0; nt < 2; ++nt) acc3[mt][nt] = zero4;
        {
            const short* pa = &frag_s[lane * 8];
            const short* pw0 = We3T + ncol0 * KP2 + quad * 8;
            const short* pw1 = We3T + ncol1 * KP2 + quad * 8;
            #pragma unroll
            for (int ks = 0; ks < 4; ++ks) {
                bf16x8 af0 = *(const bf16x8*)&pa[ks * 1024];
                bf16x8 af1 = *(const bf16x8*)&pa[ks * 1024 + 512];
                bf16x8 bw0 = *(const bf16x8*)&pw0[ks * 32];
                bf16x8 bw1 = *(const bf16x8*)&pw1[ks * 32];
                acc3[0][0] = __builtin_amdgcn_mfma_f32_16x16x32_bf16(af0, bw0, acc3[0][0], 0, 0, 0);
                acc3[1][0] = __builtin_amdgcn_mfma_f32_16x16x32_bf16(af1, bw0, acc3[1][0], 0, 0, 0);
                acc3[0][1] = __builtin_amdgcn_mfma_f32_16x16x32_bf16(af0, bw1, acc3[0][1], 0, 0, 0);
                acc3[1][1] = __builtin_amdgcn_mfma_f32_16x16x32_bf16(af1, bw1, acc3[1][1], 0, 0, 0);
            }
        }
        float b3a = p0[1024], b3b = p1[1024];
        unsigned short* bpA = &cagg_s[(quad * 4) * CAGS + ncol0];
        unsigned short* bpB = &cagg_s[(quad * 4) * CAGS + ncol1];
        #pragma unroll
        for (int mt = 0; mt < 2; ++mt)
            #pragma unroll
            for (int r = 0; r < 4; ++r) {
                bpA[(mt * 16 + r) * CAGS] = f2bf(acc3[mt][0][r] + b3a);
                bpB[(mt * 16 + r) * CAGS] = f2bf(acc3[mt][1][r] + b3b);
            }
    }
    __syncthreads();

    // ---- P7: dst-run segmented atomic flush (rows sorted by dst)
    {
        const int c = tid & 127, h = tid >> 7;
        const unsigned short* cp = &cagg_s[(h * 16) * CAGS + c];
        const int m0 = h * 16;
        float run = bfu2f(cp[0]);
        int curd = dst_s[m0];
        #pragma unroll
        for (int m = 1; m < 16; ++m) {
            int d = dst_s[m0 + m];
            float v = bfu2f(cp[m * CAGS]);
            if (d == curd) run += v;
            else { atomAddF(&mh[(size_t)curd * HID + c], run); curd = d; run = v; }
        }
        atomAddF(&mh[(size_t)curd * HID + c], run);
    }
    // ---- P8: m_v segmented flush
    if (tid < 2) {
        const int c = tid;
        float run = vw_s[0] * rel_s[c];
        int curd = dst_s[0];
        for (int m = 1; m < TE; ++m) {
            int d = dst_s[m];
            float v = vw_s[m] * rel_s[2 * m + c];
            if (d == curd) run += v;
            else { atomAddF(&mv[2 * curd + c], run); curd = d; run = v; }
        }
        atomAddF(&mv[2 * curd + c], run);
    }
}

// ---------------------------------------------------------------- node kernel (MFMA)
__global__ __launch_bounds__(256, 7)
void eg_node(const float* __restrict__ x,
             const float* __restrict__ bh1, const float* __restrict__ gh1,
             const float* __restrict__ bth1, const float* __restrict__ bh2,
             const float* __restrict__ mh, const float* __restrict__ mv,
             const int* __restrict__ deg, const short* __restrict__ wt,
             float* __restrict__ out)
{
    __shared__ __align__(16) short frag_s[7 * 2 * 64 * 8];   // 14336 B
    __shared__ float psum_s[256];
    __shared__ float mu_s[32], rs_s[32];
    __shared__ float rden_s[TN], norm_s[TN];

    const int tid  = threadIdx.x;
    const int lane = tid & 63;
    const int wid  = tid >> 6;
    const int lr   = lane & 15;
    const int quad = lane >> 4;
    const int n0w  = wid * 32;
    const int n_base = blockIdx.x * TN;

    const short* Wh1T = wt + WT_WH1;
    const short* Wh2T = wt + WT_WH2;

    if (tid < TN) {
        int n = n_base + tid;
        float den = fmaxf((float)deg[n], 1.0f);
        float rd = 1.0f / den;
        float ax = mv[2 * n] * rd + 1e-8f;
        float ay = mv[2 * n + 1] * rd + 1e-8f;
        rden_s[tid] = rd;
        norm_s[tid] = sqrtf(ax * ax + ay * ay);
    }
    if (tid < 128) {
        int4 z = {0, 0, 0, 0};
        *(int4*)&frag_s[6 * 2 * 64 * 8 + tid * 8] = z;
    }
    __syncthreads();

    {
        const int e = tid & 31, slot = tid >> 5;
        const int n = n_base + e;
        {
            int c0 = slot * 8;
            const float4 a0 = *(const float4*)&x[(size_t)n * NCH + c0];
            const float4 a1 = *(const float4*)&x[(size_t)n * NCH + c0 + 4];
            uint4 pk;
            pk.x = f2bf_pk(a0.x, a0.y); pk.y = f2bf_pk(a0.z, a0.w);
            pk.z = f2bf_pk(a1.x, a1.y); pk.w = f2bf_pk(a1.z, a1.w);
            int ks = slot >> 2, kq = slot & 3;
            *(uint4*)&frag_s[fragOff(ks, e >> 4, kq * 16 + (e & 15))] = pk;
        }
        float rd = rden_s[e];
        #pragma unroll
        for (int h = 0; h < 2; ++h) {
            int o = 8 + slot + h * 8;
            int k0 = (o - 8) * 8;
            const float4 a0 = *(const float4*)&mh[(size_t)n * HID + k0];
            const float4 a1 = *(const float4*)&mh[(size_t)n * HID + k0 + 4];
            uint4 pk;
            pk.x = f2bf_pk(a0.x * rd, a0.y * rd); pk.y = f2bf_pk(a0.z * rd, a0.w * rd);
            pk.z = f2bf_pk(a1.x * rd, a1.y * rd); pk.w = f2bf_pk(a1.z * rd, a1.w * rd);
            int ks = o >> 2, kq = o & 3;
            *(uint4*)&frag_s[fragOff(ks, e >> 4, kq * 16 + (e & 15))] = pk;
        }
    }
    if (tid < TN) {
        frag_s[fragOff(6, tid >> 4, (tid & 15))] = (short)f2bf(norm_s[tid]);
    }
    __syncthreads();

    const int ncol0 = n0w + lr;
    const int ncol1 = n0w + 16 + lr;

    f32x4 zero4 = {0.f, 0.f, 0.f, 0.f};
    f32x4 acc1[2][2];
    #pragma unroll
    for (int mt = 0; mt < 2; ++mt)
        #pragma unroll
        for (int nt = 0; nt < 2; ++nt) acc1[mt][nt] = zero4;
    {
        const short* pa = &frag_s[lane * 8];
        const short* pw0 = Wh1T + ncol0 * KN1 + quad * 8;
        const short* pw1 = Wh1T + ncol1 * KN1 + quad * 8;
        #pragma unroll
        for (int ks = 0; ks < 7; ++ks) {
            bf16x8 af0 = *(const bf16x8*)&pa[ks * 1024];
            bf16x8 af1 = *(const bf16x8*)&pa[ks * 1024 + 512];
            bf16x8 bw0 = *(const bf16x8*)&pw0[ks * 32];
            bf16x8 bw1 = *(const bf16x8*)&pw1[ks * 32];
            acc1[0][0] = __builtin_amdgcn_mfma_f32_16x16x32_bf16(af0, bw0, acc1[0][0], 0, 0, 0);
            acc1[1][0] = __builtin_amdgcn_mfma_f32_16x16x32_bf16(af1, bw0, acc1[1][0], 0, 0, 0);
            acc1[0][1] = __builtin_amdgcn_mfma_f32_16x16x32_bf16(af0, bw1, acc1[0][1], 0, 0, 0);
            acc1[1][1] = __builtin_amdgcn_mfma_f32_16x16x32_bf16(af1, bw1, acc1[1][1], 0, 0, 0);
        }
    }
    {
        float b0 = bh1[ncol0], b1 = bh1[ncol1];
        #pragma unroll
        for (int mt = 0; mt < 2; ++mt)
            #pragma unroll
            for (int r = 0; r < 4; ++r) { acc1[mt][0][r] += b0; acc1[mt][1][r] += b1; }
    }

    #pragma unroll
    for (int mt = 0; mt < 2; ++mt)
        #pragma unroll
        for (int r = 0; r < 4; ++r) {
            float s = acc1[mt][0][r] + acc1[mt][1][r];
            float q = acc1[mt][0][r] * acc1[mt][0][r] + acc1[mt][1][r] * acc1[mt][1][r];
            RED16(s); RED16(q);
            if (lr == 0) {
                int row = mt * 16 + quad * 4 + r;
                psum_s[row * 4 + wid]       = s;
                psum_s[128 + row * 4 + wid] = q;
            }
        }
    __syncthreads();
    if (tid < 32) {
        float s = 0.f, q = 0.f;
        #pragma unroll
        for (int w = 0; w < 4; ++w) {
            s += psum_s[tid * 4 + w];
            q += psum_s[128 + tid * 4 + w];
        }
        float mu = s * (1.0f / HID);
        float var = q * (1.0f / HID) - mu * mu;
        mu_s[tid] = mu;
        rs_s[tid] = rsqrtf(var + LN_EPS);
    }
    __syncthreads();

    {
        float g0 = gh1[ncol0], g1 = gh1[ncol1];
        float t0 = bth1[ncol0], t1 = bth1[ncol1];
        int ks0 = ncol0 >> 5, kq0 = (ncol0 & 31) >> 3, j0 = ncol0 & 7;
        int ks1 = ncol1 >> 5, kq1 = (ncol1 & 31) >> 3, j1 = ncol1 & 7;
        short* bp0 = &frag_s[(ks0 * 128 + kq0 * 16 + quad * 4) * 8 + j0];
        short* bp1 = &frag_s[(ks1 * 128 + kq1 * 16 + quad * 4) * 8 + j1];
        #pragma unroll
        for (int mt = 0; mt < 2; ++mt)
            #pragma unroll
            for (int r = 0; r < 4; ++r) {
                int row = mt * 16 + quad * 4 + r;
                float mu = mu_s[row], rsv = rs_s[row];
                float h0 = sp((acc1[mt][0][r] - mu) * rsv * g0 + t0);
                float h1 = sp((acc1[mt][1][r] - mu) * rsv * g1 + t1);
                bp0[mt * 512 + r * 8] = (short)f2bf(h0);
                bp1[mt * 512 + r * 8] = (short)f2bf(h1);
            }
    }
    __syncthreads();

    {
        const int col = wid * 16 + lr;
        f32x4 acc2[2] = { zero4, zero4 };
        const short* pa = &frag_s[lane * 8];
        const short* pw = Wh2T + col * KP2 + quad * 8;
        #pragma unroll
        for (int ks = 0; ks < 4; ++ks) {
            bf16x8 af0 = *(const bf16x8*)&pa[ks * 1024];
            bf16x8 af1 = *(const bf16x8*)&pa[ks * 1024 + 512];
            bf16x8 bw = *(const bf16x8*)&pw[ks * 32];
            acc2[0] = __builtin_amdgcn_mfma_f32_16x16x32_bf16(af0, bw, acc2[0], 0, 0, 0);
            acc2[1] = __builtin_amdgcn_mfma_f32_16x16x32_bf16(af1, bw, acc2[1], 0, 0, 0);
        }
        float bo = bh2[col];
        #pragma unroll
        for (int mt = 0; mt < 2; ++mt)
            #pragma unroll
            for (int r = 0; r < 4; ++r) {
                int m = mt * 16 + quad * 4 + r;
                size_t idx = (size_t)(n_base + m) * OUTC + col;
                out[idx] = x[(size_t)(n_base + m) * NCH + col] + acc2[mt][r] + bo;
            }
    }
}

// ---------------------------------------------------------------- launch
extern "C" void kernel_launch(void* const* d_in, const int* in_sizes, int n_in,
                              void* d_out, int out_size, void* d_ws, size_t ws_size,
                              hipStream_t stream)
{
    const float* x    = (const float*)d_in[0];
    const float* pos  = (const float*)d_in[1];
    const float* vel  = (const float*)d_in[2];
    const float* We1  = (const float*)d_in[3];
    const float* be1  = (const float*)d_in[4];
    const float* ge1  = (const float*)d_in[5];
    const float* bte1 = (const float*)d_in[6];
    const float* We2  = (const float*)d_in[7];
    const float* be2  = (const float*)d_in[8];
    const float* We3  = (const float*)d_in[9];
    const float* be3  = (const float*)d_in[10];
    const float* Wv1  = (const float*)d_in[11];
    const float* bv1  = (const float*)d_in[12];
    const float* gv1  = (const float*)d_in[13];
    const float* btv1 = (const float*)d_in[14];
    const float* Wv2  = (const float*)d_in[15];
    const float* bv2  = (const float*)d_in[16];
    const float* Wh1  = (const float*)d_in[17];
    const float* bh1  = (const float*)d_in[18];
    const float* gh1  = (const float*)d_in[19];
    const float* bth1 = (const float*)d_in[20];
    const float* Wh2  = (const float*)d_in[21];
    const float* bh2  = (const float*)d_in[22];
    const int*   ei   = (const int*)d_in[23];

    // workspace layout
    float* mh   = (float*)d_ws;                      // 2,560,000 f
    float* mv   = mh + (size_t)NNODE * HID;          // 40,000 f
    int*   deg  = (int*)(mv + NNODE * 2);            // 20,000 i
    int*   cur  = deg + NNODE;                       // 20,000 i
    int*   perm = cur + NNODE;                       // 640,000 i
    float* pkp  = (float*)(perm + NEDGE);            // 1,280 f
    short* wt   = (short*)(pkp + 1280);              // 110,592 s

    // zero deg only (80 KB); mh/mv are zeroed inside eg_prep
    hipMemsetAsync(deg, 0, NNODE * sizeof(int), stream);

    eg_prep<<<dim3(NEDGE / 256), dim3(256), 0, stream>>>(
        We1, Wv1, We2, We3, Wh1, Wh2,
        be1, bv1, ge1, bte1, gv1, btv1, Wv2, be2, be3, bv2,
        ei, wt, pkp, deg, mh);
    eg_scan<<<dim3(1), dim3(1024), 0, stream>>>(deg, cur);
    eg_scatter<<<dim3(NEDGE / 256), dim3(256), 0, stream>>>(ei, cur, perm);

    eg_edge<<<dim3(NEBLK), dim3(256), 0, stream>>>(
        x, pos, vel, pkp, wt, ei, perm, mh, mv);

    eg_node<<<dim3(NNODE / TN), dim3(256), 0, stream>>>(
        x, bh1, gh1, bth1, bh2, mh, mv, deg, wt, (float*)d_out);
}